// Round 4
// baseline (355.772 us; speedup 1.0000x reference)
//
#include <hip/hip_runtime.h>
#include <hip/hip_bf16.h>

// Problem constants (fixed by setup_inputs)
#define BB   16      // batches (N_t)
#define NQb  1560    // q rows per batch
#define CC   1024    // channels
#define HH   16      // heads
#define DD   64      // head dim
#define NAk  256     // keys per batch
#define CE   768     // encoder channels
#define MTOT (BB*NQb) // 24960

// 0.125 (D^-0.5) * log2(e): folded into Q-LN so softmax is exp2(s - m)
#define QSCALE 0.18033688011112042f

typedef __attribute__((ext_vector_type(8))) short bf16x8;
typedef __attribute__((ext_vector_type(4))) float f32x4;
typedef unsigned short u16;
typedef unsigned int u32;

__device__ __forceinline__ u16 f2bf(float f) {  // RNE fp32->bf16
  unsigned u = __builtin_bit_cast(unsigned, f);
  u += 0x7FFFu + ((u >> 16) & 1u);
  return (u16)(u >> 16);
}

__device__ __forceinline__ u32 cvtpk(float a, float b) {  // 2xf32 -> packed bf16
  u32 r;
  asm("v_cvt_pk_bf16_f32 %0, %1, %2" : "=v"(r) : "v"(a), "v"(b));
  return r;
}

__device__ __forceinline__ void gl2lds16(const void* g, void* l) {
  __builtin_amdgcn_global_load_lds(
      (const __attribute__((address_space(1))) void*)g,
      (__attribute__((address_space(3))) void*)l, 16, 0, 0);
}

__device__ __forceinline__ f32x4 mfma16(bf16x8 a, bf16x8 b, f32x4 c) {
  return __builtin_amdgcn_mfma_f32_16x16x32_bf16(a, b, c, 0, 0, 0);
}

// ---------------------------------------------------------------------------
// fp32 -> bf16 bulk convert
// ---------------------------------------------------------------------------
__global__ __launch_bounds__(256) void conv_f2b(const float* __restrict__ s,
                                                u16* __restrict__ d, int n4) {
  int i = blockIdx.x * 256 + threadIdx.x;
  if (i >= n4) return;
  float4 v = reinterpret_cast<const float4*>(s)[i];
  ushort4 o;
  o.x = f2bf(v.x); o.y = f2bf(v.y); o.z = f2bf(v.z); o.w = f2bf(v.w);
  reinterpret_cast<ushort4*>(d)[i] = o;
}

// ---------------------------------------------------------------------------
// bf16 MFMA GEMM: out = A[M,KD] @ W[N,KD]^T (+bias, + epilogue)
// 128x128 tile, BK=64, 4 waves (2x2). NXT = col tiles (gridDim.x).
// T1 bijective XCD swizzle: consecutive blocks on one XCD share row-panels.
// EPI: 0 = per-head LN (eps 1e-6), scaled by QSCALE -> bf16 o_bf [M,CC]
//      1 = KV: cols<CC get LN (eps 1e-5) -> Kbf[b][h][na][d];
//              cols>=CC -> Vt[b][h][d][na]  (both bf16)
//      2 = bias -> fp32 o_f [M,CC]
// ---------------------------------------------------------------------------
template <int KD, int EPI, int NXT>
__global__ __launch_bounds__(256) void gemm_bf16(
    const u16* __restrict__ A, const u16* __restrict__ W,
    const float* __restrict__ bias, const float* __restrict__ lnw,
    const float* __restrict__ lnb, u16* __restrict__ o_bf,
    u16* __restrict__ o_bf2, float* __restrict__ o_f) {
  __shared__ u16 As[128 * 64];
  __shared__ u16 Bs[128 * 64];
  const int tid = threadIdx.x;
  const int l = tid & 63, wid = tid >> 6;
  const int wr = wid >> 1, wc = wid & 1;

  // XCD-aware remap (nwg % 8 == 0 for all instantiations)
  const int orig = (int)blockIdx.x + NXT * (int)blockIdx.y;
  const int q8 = (NXT * (int)gridDim.y) >> 3;
  const int nid = (orig & 7) * q8 + (orig >> 3);
  const int row0 = (nid / NXT) * 128, col0 = (nid % NXT) * 128;

  const int srow = tid >> 3;
  const int scb = ((((tid & 7) * 16) ^ ((srow & 7) << 4)) >> 1);
  const u16* gA = A + (size_t)(row0 + srow) * KD + scb;
  const u16* gB = W + (size_t)(col0 + srow) * KD + scb;
  char* lA = (char*)As + tid * 16;
  char* lB = (char*)Bs + tid * 16;

  int aoff[4][2], boff[4][2];
#pragma unroll
  for (int m = 0; m < 4; ++m)
#pragma unroll
    for (int kk = 0; kk < 2; ++kk) {
      int ra = wr * 64 + m * 16 + (l & 15);
      int rb = wc * 64 + m * 16 + (l & 15);
      int cb = (l >> 4) * 16 + kk * 64;
      aoff[m][kk] = ra * 128 + (cb ^ ((ra & 7) << 4));
      boff[m][kk] = rb * 128 + (cb ^ ((rb & 7) << 4));
    }

  f32x4 acc[4][4];
#pragma unroll
  for (int m = 0; m < 4; ++m)
#pragma unroll
    for (int n = 0; n < 4; ++n) acc[m][n] = (f32x4){0.f, 0.f, 0.f, 0.f};

  for (int k0 = 0; k0 < KD; k0 += 64) {
    __syncthreads();
#pragma unroll
    for (int i = 0; i < 4; ++i) {
      gl2lds16(gA + (size_t)i * 32 * KD + k0, lA + i * 4096);
      gl2lds16(gB + (size_t)i * 32 * KD + k0, lB + i * 4096);
    }
    __syncthreads();
    bf16x8 af[4][2], bfr[4][2];
#pragma unroll
    for (int m = 0; m < 4; ++m)
#pragma unroll
      for (int kk = 0; kk < 2; ++kk) {
        af[m][kk]  = *(const bf16x8*)((const char*)As + aoff[m][kk]);
        bfr[m][kk] = *(const bf16x8*)((const char*)Bs + boff[m][kk]);
      }
#pragma unroll
    for (int kk = 0; kk < 2; ++kk)
#pragma unroll
      for (int m = 0; m < 4; ++m)
#pragma unroll
        for (int n = 0; n < 4; ++n)
          acc[m][n] = mfma16(af[m][kk], bfr[n][kk], acc[m][n]);
  }

  const int colw = col0 + wc * 64;
  float bv[4];
#pragma unroll
  for (int n = 0; n < 4; ++n) bv[n] = bias[colw + n * 16 + (l & 15)];

  if constexpr (EPI == 2) {
#pragma unroll
    for (int m = 0; m < 4; ++m)
#pragma unroll
      for (int reg = 0; reg < 4; ++reg) {
        int grow = row0 + wr * 64 + m * 16 + (l >> 4) * 4 + reg;
#pragma unroll
        for (int n = 0; n < 4; ++n)
          o_f[(size_t)grow * CC + colw + n * 16 + (l & 15)] =
              acc[m][n][reg] + bv[n];
      }
    return;
  }

  if constexpr (EPI == 0) {
    float lwv[4], lbv[4];
#pragma unroll
    for (int n = 0; n < 4; ++n) {
      lwv[n] = lnw[n * 16 + (l & 15)] * QSCALE;
      lbv[n] = lnb[n * 16 + (l & 15)] * QSCALE;
    }
    const int head = colw >> 6;
#pragma unroll
    for (int m = 0; m < 4; ++m)
#pragma unroll
      for (int reg = 0; reg < 4; ++reg) {
        float tv[4], s = 0.f, ss = 0.f;
#pragma unroll
        for (int n = 0; n < 4; ++n) {
          tv[n] = acc[m][n][reg] + bv[n];
          s += tv[n]; ss += tv[n] * tv[n];
        }
#pragma unroll
        for (int off = 1; off < 16; off <<= 1) {
          s  += __shfl_xor(s, off, 16);
          ss += __shfl_xor(ss, off, 16);
        }
        float mean = s * (1.f / 64.f);
        float var  = ss * (1.f / 64.f) - mean * mean;
        float rs   = rsqrtf(var + 1e-6f);
        int grow = row0 + wr * 64 + m * 16 + (l >> 4) * 4 + reg;
        u16* dst = o_bf + (size_t)grow * CC + head * 64;
#pragma unroll
        for (int n = 0; n < 4; ++n)
          dst[n * 16 + (l & 15)] = f2bf((tv[n] - mean) * rs * lwv[n] + lbv[n]);
      }
    return;
  }

  if constexpr (EPI == 1) {
    const bool isK = (colw < CC);
    const int head = (isK ? colw : (colw - CC)) >> 6;
    if (isK) {
      float lwv[4], lbv[4];
#pragma unroll
      for (int n = 0; n < 4; ++n) {
        lwv[n] = lnw[n * 16 + (l & 15)];
        lbv[n] = lnb[n * 16 + (l & 15)];
      }
#pragma unroll
      for (int m = 0; m < 4; ++m)
#pragma unroll
        for (int reg = 0; reg < 4; ++reg) {
          float tv[4], s = 0.f, ss = 0.f;
#pragma unroll
          for (int n = 0; n < 4; ++n) {
            tv[n] = acc[m][n][reg] + bv[n];
            s += tv[n]; ss += tv[n] * tv[n];
          }
#pragma unroll
          for (int off = 1; off < 16; off <<= 1) {
            s  += __shfl_xor(s, off, 16);
            ss += __shfl_xor(ss, off, 16);
          }
          float mean = s * (1.f / 64.f);
          float var  = ss * (1.f / 64.f) - mean * mean;
          float rs   = rsqrtf(var + 1e-5f);
          int grow = row0 + wr * 64 + m * 16 + (l >> 4) * 4 + reg;
          int bb = grow >> 8, na = grow & 255;
          u16* dst = o_bf + (size_t)((bb * HH + head) * NAk + na) * DD;
#pragma unroll
          for (int n = 0; n < 4; ++n)
            dst[n * 16 + (l & 15)] =
                f2bf((tv[n] - mean) * rs * lwv[n] + lbv[n]);
        }
    } else {
#pragma unroll
      for (int m = 0; m < 4; ++m)
#pragma unroll
        for (int reg = 0; reg < 4; ++reg) {
          int grow = row0 + wr * 64 + m * 16 + (l >> 4) * 4 + reg;
          int bb = grow >> 8, na = grow & 255;
          u16* dst = o_bf2 + (size_t)(bb * HH + head) * DD * NAk + na;
#pragma unroll
          for (int n = 0; n < 4; ++n) {
            int d = n * 16 + (l & 15);
            dst[(size_t)d * NAk] = f2bf(acc[m][n][reg] + bv[n]);
          }
        }
    }
    return;
  }
}

// ---------------------------------------------------------------------------
// MFMA attention v4: online softmax over 4x64-key chunks, barrier-free.
// Swapped QK^T (S^T = K.Q^T, q lane-local); T13 defer-max (THR=8 in exp2
// domain => P <= 256); T12 cvt_pk pack; per-wave-private 4KB P buffer
// (in-order DS => no syncthreads); deferred 1/l via bpermute in epilogue;
// T5 setprio around MFMA clusters.
// block = 256 (4 waves x 32 q-rows); grid = (13, HH, BB)
// ---------------------------------------------------------------------------
__global__ __launch_bounds__(256) void attn_mfma(
    const u16* __restrict__ Qbf, const u16* __restrict__ Kbf,
    const u16* __restrict__ Vtbf, u16* __restrict__ Obf) {
  __shared__ u16 P[4][32][64];  // 16KB total; per-wave [32 q][64 keys]
  const int tid = threadIdx.x, l = tid & 63, wid = tid >> 6;
  const int g = l >> 4, ql = l & 15;
  const int qb = blockIdx.x, h = blockIdx.y, b = blockIdx.z;
  const size_t kvbase = (size_t)(b * HH + h) * (NAk * DD);
  const u16* Kp = Kbf + kvbase;
  const u16* Vp = Vtbf + kvbase;
  char* Pw = (char*)&P[wid][0][0];
  const int swz = (ql & 7) << 4;  // row-XOR swizzle ((q&7) == (ql&7))

  // Q fragments (B-operand: col q = m*16+ql, k = d)
  bf16x8 qf[2][2];
#pragma unroll
  for (int m = 0; m < 2; ++m) {
    int qrow = qb * 128 + wid * 32 + m * 16 + ql;
    int qrc = min(qrow, NQb - 1);
    const u16* p = Qbf + (size_t)(b * NQb + qrc) * CC + h * DD + g * 8;
    qf[m][0] = *(const bf16x8*)(p);
    qf[m][1] = *(const bf16x8*)(p + 32);
  }

  f32x4 oacc[2][4];
#pragma unroll
  for (int m = 0; m < 2; ++m)
#pragma unroll
    for (int n = 0; n < 4; ++n) oacc[m][n] = (f32x4){0.f, 0.f, 0.f, 0.f};
  float mrun[2] = {0.f, 0.f}, lsum[2] = {0.f, 0.f};

#pragma unroll
  for (int c = 0; c < 4; ++c) {
    // --- QK^T chunk: sf[m][n] -> col q = m*16+ql, key = c*64+n*16+g*4+reg
    f32x4 sf[2][4];
#pragma unroll
    for (int m = 0; m < 2; ++m)
#pragma unroll
      for (int n = 0; n < 4; ++n) sf[m][n] = (f32x4){0.f, 0.f, 0.f, 0.f};
    __builtin_amdgcn_s_setprio(1);
#pragma unroll
    for (int n = 0; n < 4; ++n) {
      const u16* kp = Kp + (size_t)(c * 64 + n * 16 + ql) * DD + g * 8;
      bf16x8 ka0 = *(const bf16x8*)(kp);
      bf16x8 ka1 = *(const bf16x8*)(kp + 32);
      sf[0][n] = mfma16(ka0, qf[0][0], sf[0][n]);
      sf[0][n] = mfma16(ka1, qf[0][1], sf[0][n]);
      sf[1][n] = mfma16(ka0, qf[1][0], sf[1][n]);
      sf[1][n] = mfma16(ka1, qf[1][1], sf[1][n]);
    }
    __builtin_amdgcn_s_setprio(0);

    // --- row max (lane-local 16 + 2 cross-group shuffles)
    float rm[2];
#pragma unroll
    for (int m = 0; m < 2; ++m) {
      float v = sf[m][0][0];
#pragma unroll
      for (int n = 0; n < 4; ++n)
#pragma unroll
        for (int reg = 0; reg < 4; ++reg) v = fmaxf(v, sf[m][n][reg]);
      v = fmaxf(v, __shfl_xor(v, 16));
      v = fmaxf(v, __shfl_xor(v, 32));
      rm[m] = v;
    }
    if (c == 0) {
      mrun[0] = rm[0]; mrun[1] = rm[1];
    } else {
      // T13 defer-max: skip rescale unless max grew past THR=8 (P <= 2^8)
      bool ok = (rm[0] <= mrun[0] + 8.f) && (rm[1] <= mrun[1] + 8.f);
      if (!__all(ok)) {
#pragma unroll
        for (int m = 0; m < 2; ++m) {
          float mn = fmaxf(mrun[m], rm[m]);
          float al = exp2f(mrun[m] - mn);
          mrun[m] = mn;
          lsum[m] *= al;
          float ar[4];
#pragma unroll
          for (int reg = 0; reg < 4; ++reg) ar[reg] = __shfl(al, g * 4 + reg);
#pragma unroll
          for (int n = 0; n < 4; ++n)
#pragma unroll
            for (int reg = 0; reg < 4; ++reg) oacc[m][n][reg] *= ar[reg];
        }
      }
    }

    // --- exp2, sum, pack (unnormalized P) to per-wave LDS
#pragma unroll
    for (int m = 0; m < 2; ++m) {
      float cs = 0.f;
#pragma unroll
      for (int n = 0; n < 4; ++n)
#pragma unroll
        for (int reg = 0; reg < 4; ++reg) {
          float e = exp2f(sf[m][n][reg] - mrun[m]);
          sf[m][n][reg] = e;
          cs += e;
        }
      cs += __shfl_xor(cs, 16);
      cs += __shfl_xor(cs, 32);
      lsum[m] += cs;
      char* rowp = Pw + (m * 16 + ql) * 128;
#pragma unroll
      for (int n = 0; n < 4; ++n) {
        u32 w0 = cvtpk(sf[m][n][0], sf[m][n][1]);
        u32 w1 = cvtpk(sf[m][n][2], sf[m][n][3]);
        *(uint2*)(rowp + ((n * 32 + g * 8) ^ swz)) = make_uint2(w0, w1);
      }
    }

    // --- PV chunk: O += P(chunk) . V(chunk)
    __builtin_amdgcn_s_setprio(1);
#pragma unroll
    for (int ks = 0; ks < 2; ++ks) {
      bf16x8 pa[2], vb[4];
#pragma unroll
      for (int m = 0; m < 2; ++m)
        pa[m] = *(const bf16x8*)(Pw + (m * 16 + ql) * 128 +
                                 ((ks * 64 + g * 16) ^ swz));
#pragma unroll
      for (int n = 0; n < 4; ++n)
        vb[n] = *(const bf16x8*)(Vp + (size_t)(n * 16 + ql) * NAk + c * 64 +
                                 ks * 32 + g * 8);
#pragma unroll
      for (int m = 0; m < 2; ++m)
#pragma unroll
        for (int n = 0; n < 4; ++n) oacc[m][n] = mfma16(pa[m], vb[n], oacc[m][n]);
    }
    __builtin_amdgcn_s_setprio(0);
  }

  // --- epilogue: redistribute 1/l to (g,reg) rows, normalize, store bf16
#pragma unroll
  for (int m = 0; m < 2; ++m) {
    float inv[4];
#pragma unroll
    for (int reg = 0; reg < 4; ++reg)
      inv[reg] = 1.f / __shfl(lsum[m], g * 4 + reg);
#pragma unroll
    for (int reg = 0; reg < 4; ++reg) {
      int qrow = qb * 128 + wid * 32 + m * 16 + g * 4 + reg;
      if (qrow < NQb) {
        u16* dst = Obf + (size_t)(b * NQb + qrow) * CC + h * DD;
#pragma unroll
        for (int n = 0; n < 4; ++n)
          dst[n * 16 + ql] = f2bf(oacc[m][n][reg] * inv[reg]);
      }
    }
  }
}

// ---------------------------------------------------------------------------
extern "C" void kernel_launch(void* const* d_in, const int* in_sizes, int n_in,
                              void* d_out, int out_size, void* d_ws,
                              size_t ws_size, hipStream_t stream) {
  const float* x      = (const float*)d_in[0];
  const float* enc    = (const float*)d_in[1];
  const float* q_w    = (const float*)d_in[2];
  const float* q_b    = (const float*)d_in[3];
  const float* kv_w   = (const float*)d_in[4];
  const float* kv_b   = (const float*)d_in[5];
  const float* proj_w = (const float*)d_in[6];
  const float* proj_b = (const float*)d_in[7];
  const float* qn_w   = (const float*)d_in[8];
  const float* qn_b   = (const float*)d_in[9];
  const float* kn_w   = (const float*)d_in[10];
  const float* kn_b   = (const float*)d_in[11];
  float* out = (float*)d_out;

  u16* ws = (u16*)d_ws;
  size_t off = 0;
  u16* Xbf  = ws + off; off += (size_t)MTOT * CC;   // also reused as O
  u16* Qbf  = ws + off; off += (size_t)MTOT * CC;
  u16* Ebf  = ws + off; off += (size_t)BB * NAk * CE;
  u16* QWb  = ws + off; off += (size_t)CC * CC;
  u16* KVWb = ws + off; off += (size_t)2 * CC * CE;
  u16* PWb  = ws + off; off += (size_t)CC * CC;
  u16* Kbf  = ws + off; off += (size_t)BB * HH * NAk * DD;
  u16* Vtbf = ws + off; off += (size_t)BB * HH * NAk * DD;

  auto cvt = [&](const float* s, u16* d, size_t n) {
    int n4 = (int)(n / 4);
    conv_f2b<<<(n4 + 255) / 256, 256, 0, stream>>>(s, d, n4);
  };
  cvt(x, Xbf, (size_t)MTOT * CC);
  cvt(enc, Ebf, (size_t)BB * NAk * CE);
  cvt(q_w, QWb, (size_t)CC * CC);
  cvt(kv_w, KVWb, (size_t)2 * CC * CE);
  cvt(proj_w, PWb, (size_t)CC * CC);

  gemm_bf16<CC, 0, 8><<<dim3(8, MTOT / 128), 256, 0, stream>>>(
      Xbf, QWb, q_b, qn_w, qn_b, Qbf, nullptr, nullptr);
  gemm_bf16<CE, 1, 16><<<dim3(16, (BB * NAk) / 128), 256, 0, stream>>>(
      Ebf, KVWb, kv_b, kn_w, kn_b, Kbf, Vtbf, nullptr);
  attn_mfma<<<dim3((NQb + 127) / 128, HH, BB), 256, 0, stream>>>(Qbf, Kbf,
                                                                 Vtbf, Xbf);
  gemm_bf16<CC, 2, 8><<<dim3(8, MTOT / 128), 256, 0, stream>>>(
      Xbf, PWb, proj_b, nullptr, nullptr, nullptr, nullptr, out);
}

// Round 5
// 274.607 us; speedup vs baseline: 1.2956x; 1.2956x over previous
//
#include <hip/hip_runtime.h>
#include <hip/hip_bf16.h>

// Problem constants (fixed by setup_inputs)
#define BB   16      // batches (N_t)
#define NQb  1560    // q rows per batch
#define CC   1024    // channels
#define HH   16      // heads
#define DD   64      // head dim
#define NAk  256     // keys per batch
#define CE   768     // encoder channels
#define MTOT (BB*NQb) // 24960
#define NTIL ((NQb + 31) / 32)  // 49 q-tiles of 32 rows

// 0.125 (D^-0.5) * log2(e): folded into Q-LN so softmax is exp2(s) directly.
// |s| <= 64*0.1803 = 11.54 (Cauchy-Schwarz on unit-variance LN outputs), so
// exp2 needs no max subtraction at all.
#define QSCALE 0.18033688011112042f

typedef __attribute__((ext_vector_type(8))) short bf16x8;
typedef __attribute__((ext_vector_type(4))) float f32x4;
typedef unsigned short u16;
typedef unsigned int u32;

__device__ __forceinline__ u16 f2bf(float f) {  // RNE fp32->bf16
  unsigned u = __builtin_bit_cast(unsigned, f);
  u += 0x7FFFu + ((u >> 16) & 1u);
  return (u16)(u >> 16);
}

__device__ __forceinline__ u32 cvtpk(float a, float b) {  // 2xf32 -> packed bf16
  u32 r;
  asm("v_cvt_pk_bf16_f32 %0, %1, %2" : "=v"(r) : "v"(a), "v"(b));
  return r;
}

__device__ __forceinline__ void gl2lds16(const void* g, void* l) {
  __builtin_amdgcn_global_load_lds(
      (const __attribute__((address_space(1))) void*)g,
      (__attribute__((address_space(3))) void*)l, 16, 0, 0);
}

__device__ __forceinline__ f32x4 mfma16(bf16x8 a, bf16x8 b, f32x4 c) {
  return __builtin_amdgcn_mfma_f32_16x16x32_bf16(a, b, c, 0, 0, 0);
}

// ---------------------------------------------------------------------------
// fp32 -> bf16 bulk convert
// ---------------------------------------------------------------------------
__global__ __launch_bounds__(256) void conv_f2b(const float* __restrict__ s,
                                                u16* __restrict__ d, int n4) {
  int i = blockIdx.x * 256 + threadIdx.x;
  if (i >= n4) return;
  float4 v = reinterpret_cast<const float4*>(s)[i];
  ushort4 o;
  o.x = f2bf(v.x); o.y = f2bf(v.y); o.z = f2bf(v.z); o.w = f2bf(v.w);
  reinterpret_cast<ushort4*>(d)[i] = o;
}

// ---------------------------------------------------------------------------
// bf16 MFMA GEMM: out = A[M,KD] @ W[N,KD]^T (+bias, + epilogue)
// 128x128 tile, BK=64, 4 waves (2x2). NXT = col tiles.
// T1 bijective XCD swizzle. (unchanged from R4 — known good)
// EPI: 0 = per-head LN (eps 1e-6), scaled by QSCALE -> bf16 o_bf [M,CC]
//      1 = KV: cols<CC get LN (eps 1e-5) -> Kbf[b][h][na][d];
//              cols>=CC -> Vt[b][h][d][na]  (both bf16)
//      2 = bias -> fp32 o_f [M,CC]
// ---------------------------------------------------------------------------
template <int KD, int EPI, int NXT>
__global__ __launch_bounds__(256) void gemm_bf16(
    const u16* __restrict__ A, const u16* __restrict__ W,
    const float* __restrict__ bias, const float* __restrict__ lnw,
    const float* __restrict__ lnb, u16* __restrict__ o_bf,
    u16* __restrict__ o_bf2, float* __restrict__ o_f) {
  __shared__ u16 As[128 * 64];
  __shared__ u16 Bs[128 * 64];
  const int tid = threadIdx.x;
  const int l = tid & 63, wid = tid >> 6;
  const int wr = wid >> 1, wc = wid & 1;

  const int orig = (int)blockIdx.x + NXT * (int)blockIdx.y;
  const int q8 = (NXT * (int)gridDim.y) >> 3;
  const int nid = (orig & 7) * q8 + (orig >> 3);
  const int row0 = (nid / NXT) * 128, col0 = (nid % NXT) * 128;

  const int srow = tid >> 3;
  const int scb = ((((tid & 7) * 16) ^ ((srow & 7) << 4)) >> 1);
  const u16* gA = A + (size_t)(row0 + srow) * KD + scb;
  const u16* gB = W + (size_t)(col0 + srow) * KD + scb;
  char* lA = (char*)As + tid * 16;
  char* lB = (char*)Bs + tid * 16;

  int aoff[4][2], boff[4][2];
#pragma unroll
  for (int m = 0; m < 4; ++m)
#pragma unroll
    for (int kk = 0; kk < 2; ++kk) {
      int ra = wr * 64 + m * 16 + (l & 15);
      int rb = wc * 64 + m * 16 + (l & 15);
      int cb = (l >> 4) * 16 + kk * 64;
      aoff[m][kk] = ra * 128 + (cb ^ ((ra & 7) << 4));
      boff[m][kk] = rb * 128 + (cb ^ ((rb & 7) << 4));
    }

  f32x4 acc[4][4];
#pragma unroll
  for (int m = 0; m < 4; ++m)
#pragma unroll
    for (int n = 0; n < 4; ++n) acc[m][n] = (f32x4){0.f, 0.f, 0.f, 0.f};

  for (int k0 = 0; k0 < KD; k0 += 64) {
    __syncthreads();
#pragma unroll
    for (int i = 0; i < 4; ++i) {
      gl2lds16(gA + (size_t)i * 32 * KD + k0, lA + i * 4096);
      gl2lds16(gB + (size_t)i * 32 * KD + k0, lB + i * 4096);
    }
    __syncthreads();
    bf16x8 af[4][2], bfr[4][2];
#pragma unroll
    for (int m = 0; m < 4; ++m)
#pragma unroll
      for (int kk = 0; kk < 2; ++kk) {
        af[m][kk]  = *(const bf16x8*)((const char*)As + aoff[m][kk]);
        bfr[m][kk] = *(const bf16x8*)((const char*)Bs + boff[m][kk]);
      }
#pragma unroll
    for (int kk = 0; kk < 2; ++kk)
#pragma unroll
      for (int m = 0; m < 4; ++m)
#pragma unroll
        for (int n = 0; n < 4; ++n)
          acc[m][n] = mfma16(af[m][kk], bfr[n][kk], acc[m][n]);
  }

  const int colw = col0 + wc * 64;
  float bv[4];
#pragma unroll
  for (int n = 0; n < 4; ++n) bv[n] = bias[colw + n * 16 + (l & 15)];

  if constexpr (EPI == 2) {
#pragma unroll
    for (int m = 0; m < 4; ++m)
#pragma unroll
      for (int reg = 0; reg < 4; ++reg) {
        int grow = row0 + wr * 64 + m * 16 + (l >> 4) * 4 + reg;
#pragma unroll
        for (int n = 0; n < 4; ++n)
          o_f[(size_t)grow * CC + colw + n * 16 + (l & 15)] =
              acc[m][n][reg] + bv[n];
      }
    return;
  }

  if constexpr (EPI == 0) {
    float lwv[4], lbv[4];
#pragma unroll
    for (int n = 0; n < 4; ++n) {
      lwv[n] = lnw[n * 16 + (l & 15)] * QSCALE;
      lbv[n] = lnb[n * 16 + (l & 15)] * QSCALE;
    }
    const int head = colw >> 6;
#pragma unroll
    for (int m = 0; m < 4; ++m)
#pragma unroll
      for (int reg = 0; reg < 4; ++reg) {
        float tv[4], s = 0.f, ss = 0.f;
#pragma unroll
        for (int n = 0; n < 4; ++n) {
          tv[n] = acc[m][n][reg] + bv[n];
          s += tv[n]; ss += tv[n] * tv[n];
        }
#pragma unroll
        for (int off = 1; off < 16; off <<= 1) {
          s  += __shfl_xor(s, off, 16);
          ss += __shfl_xor(ss, off, 16);
        }
        float mean = s * (1.f / 64.f);
        float var  = ss * (1.f / 64.f) - mean * mean;
        float rs   = rsqrtf(var + 1e-6f);
        int grow = row0 + wr * 64 + m * 16 + (l >> 4) * 4 + reg;
        u16* dst = o_bf + (size_t)grow * CC + head * 64;
#pragma unroll
        for (int n = 0; n < 4; ++n)
          dst[n * 16 + (l & 15)] = f2bf((tv[n] - mean) * rs * lwv[n] + lbv[n]);
      }
    return;
  }

  if constexpr (EPI == 1) {
    const bool isK = (colw < CC);
    const int head = (isK ? colw : (colw - CC)) >> 6;
    if (isK) {
      float lwv[4], lbv[4];
#pragma unroll
      for (int n = 0; n < 4; ++n) {
        lwv[n] = lnw[n * 16 + (l & 15)];
        lbv[n] = lnb[n * 16 + (l & 15)];
      }
#pragma unroll
      for (int m = 0; m < 4; ++m)
#pragma unroll
        for (int reg = 0; reg < 4; ++reg) {
          float tv[4], s = 0.f, ss = 0.f;
#pragma unroll
          for (int n = 0; n < 4; ++n) {
            tv[n] = acc[m][n][reg] + bv[n];
            s += tv[n]; ss += tv[n] * tv[n];
          }
#pragma unroll
          for (int off = 1; off < 16; off <<= 1) {
            s  += __shfl_xor(s, off, 16);
            ss += __shfl_xor(ss, off, 16);
          }
          float mean = s * (1.f / 64.f);
          float var  = ss * (1.f / 64.f) - mean * mean;
          float rs   = rsqrtf(var + 1e-5f);
          int grow = row0 + wr * 64 + m * 16 + (l >> 4) * 4 + reg;
          int bb = grow >> 8, na = grow & 255;
          u16* dst = o_bf + (size_t)((bb * HH + head) * NAk + na) * DD;
#pragma unroll
          for (int n = 0; n < 4; ++n)
            dst[n * 16 + (l & 15)] =
                f2bf((tv[n] - mean) * rs * lwv[n] + lbv[n]);
        }
    } else {
#pragma unroll
      for (int m = 0; m < 4; ++m)
#pragma unroll
        for (int reg = 0; reg < 4; ++reg) {
          int grow = row0 + wr * 64 + m * 16 + (l >> 4) * 4 + reg;
          int bb = grow >> 8, na = grow & 255;
          u16* dst = o_bf2 + (size_t)(bb * HH + head) * DD * NAk + na;
#pragma unroll
          for (int n = 0; n < 4; ++n) {
            int d = n * 16 + (l & 15);
            dst[(size_t)d * NAk] = f2bf(acc[m][n][reg] + bv[n]);
          }
        }
    }
    return;
  }
}

// ---------------------------------------------------------------------------
// MFMA attention v5: PERSISTENT per-(b,h) block. grid = (HH, BB) = 256 blocks
// (1 per CU), 768 threads = 12 waves (3/SIMD). K [256][64] + Vt [64][256]
// staged ONCE into swizzled LDS (64KB), then waves independently sweep
// 32-row q-tiles (49 tiles, wave-strided). Swapped QK^T (q lane-local),
// NO-MAX softmax (|s| <= 11.54 guaranteed by LN norm bound), unnormalized
// bf16 P via cvt_pk into per-wave-private LDS, deferred 1/l in epilogue.
// LDS total: 32+32+48 = 112KB -> 1 block/CU.
// ---------------------------------------------------------------------------
__global__ __launch_bounds__(768) void attn_mfma(
    const u16* __restrict__ Qbf, const u16* __restrict__ Kbf,
    const u16* __restrict__ Vtbf, u16* __restrict__ Obf) {
  __shared__ u16 Ks[256 * 64];    // 32KB [key][d], row-XOR swizzled
  __shared__ u16 Vts[64 * 256];   // 32KB [d][key], row-XOR swizzled
  __shared__ u16 P[12][32][64];   // 48KB per-wave [32 q][64 keys]
  const int tid = threadIdx.x, l = tid & 63, wid = tid >> 6;
  const int g = l >> 4, ql = l & 15;
  const int h = blockIdx.x, b = blockIdx.y;
  const size_t kvbase = (size_t)(b * HH + h) * (NAk * DD);
  const u16* Kp = Kbf + kvbase;
  const u16* Vp = Vtbf + kvbase;
  char* Pw = (char*)&P[wid][0][0];
  const int swz = (ql & 7) << 4;  // row-XOR swizzle ((row&7) == (ql&7))

  // ---- stage K (2048 x 16B) + Vt (2048 x 16B), pre-swizzled source
  for (int idx = tid; idx < 4096; idx += 768) {
    if (idx < 2048) {
      int kr = idx >> 3, kc = idx & 7;  // row (128B), 16B chunk
      gl2lds16(Kp + kr * 64 + (((kc * 16) ^ ((kr & 7) << 4)) >> 1),
               (char*)Ks + idx * 16);
    } else {
      int j = idx - 2048;
      int vr = j >> 5, vc = j & 31;     // row (512B), 16B chunk
      gl2lds16(Vp + vr * 256 + (((vc * 16) ^ ((vr & 7) << 4)) >> 1),
               (char*)Vts + j * 16);
    }
  }
  __syncthreads();  // K/V staged; everything below is barrier-free

  const u16* Qb0 = Qbf + (size_t)b * NQb * CC + h * DD;
  u16* Ob0 = Obf + (size_t)b * NQb * CC + h * DD;

  for (int t = wid; t < NTIL; t += 12) {
    const int qr0 = t * 32;
    // Q fragments (B-operand: col q = m*16+ql, k = d)
    bf16x8 qf[2][2];
#pragma unroll
    for (int m = 0; m < 2; ++m) {
      int qrow = min(qr0 + m * 16 + ql, NQb - 1);
      const u16* p = Qb0 + (size_t)qrow * CC + g * 8;
      qf[m][0] = *(const bf16x8*)(p);
      qf[m][1] = *(const bf16x8*)(p + 32);
    }

    f32x4 oacc[2][4];
#pragma unroll
    for (int m = 0; m < 2; ++m)
#pragma unroll
      for (int n = 0; n < 4; ++n) oacc[m][n] = (f32x4){0.f, 0.f, 0.f, 0.f};
    float lsum[2] = {0.f, 0.f};

#pragma unroll
    for (int c = 0; c < 4; ++c) {
      // --- QK^T chunk: sf[m][n] -> col q = m*16+ql, key = c*64+n*16+g*4+reg
      f32x4 sf[2][4];
#pragma unroll
      for (int m = 0; m < 2; ++m)
#pragma unroll
        for (int n = 0; n < 4; ++n) sf[m][n] = (f32x4){0.f, 0.f, 0.f, 0.f};
      __builtin_amdgcn_s_setprio(1);
#pragma unroll
      for (int n = 0; n < 4; ++n) {
        const char* kbase = (const char*)Ks + (c * 64 + n * 16 + ql) * 128;
        bf16x8 ka0 = *(const bf16x8*)(kbase + ((g * 16) ^ swz));
        bf16x8 ka1 = *(const bf16x8*)(kbase + ((g * 16 + 64) ^ swz));
        sf[0][n] = mfma16(ka0, qf[0][0], sf[0][n]);
        sf[0][n] = mfma16(ka1, qf[0][1], sf[0][n]);
        sf[1][n] = mfma16(ka0, qf[1][0], sf[1][n]);
        sf[1][n] = mfma16(ka1, qf[1][1], sf[1][n]);
      }
      __builtin_amdgcn_s_setprio(0);

      // --- exp2 (no max needed), lane-local sum, pack unnormalized P
#pragma unroll
      for (int m = 0; m < 2; ++m) {
        float cs = 0.f;
#pragma unroll
        for (int n = 0; n < 4; ++n)
#pragma unroll
          for (int reg = 0; reg < 4; ++reg) {
            float e = exp2f(sf[m][n][reg]);
            sf[m][n][reg] = e;
            cs += e;
          }
        lsum[m] += cs;
        char* rowp = Pw + (m * 16 + ql) * 128;
#pragma unroll
        for (int n = 0; n < 4; ++n) {
          u32 w0 = cvtpk(sf[m][n][0], sf[m][n][1]);
          u32 w1 = cvtpk(sf[m][n][2], sf[m][n][3]);
          *(uint2*)(rowp + ((n * 32 + g * 8) ^ swz)) = make_uint2(w0, w1);
        }
      }

      // --- PV chunk: O += P(chunk) . V(chunk)
      __builtin_amdgcn_s_setprio(1);
#pragma unroll
      for (int ks = 0; ks < 2; ++ks) {
        bf16x8 pa[2], vb[4];
#pragma unroll
        for (int m = 0; m < 2; ++m)
          pa[m] = *(const bf16x8*)(Pw + (m * 16 + ql) * 128 +
                                   ((ks * 64 + g * 16) ^ swz));
#pragma unroll
        for (int n = 0; n < 4; ++n)
          vb[n] = *(const bf16x8*)((const char*)Vts + (n * 16 + ql) * 512 +
                                   ((c * 128 + ks * 64 + g * 16) ^ swz));
#pragma unroll
        for (int m = 0; m < 2; ++m)
#pragma unroll
          for (int n = 0; n < 4; ++n)
            oacc[m][n] = mfma16(pa[m], vb[n], oacc[m][n]);
      }
      __builtin_amdgcn_s_setprio(0);
    }

    // --- epilogue: cross-group l reduce (once), redistribute, store bf16
#pragma unroll
    for (int m = 0; m < 2; ++m) {
      lsum[m] += __shfl_xor(lsum[m], 16);
      lsum[m] += __shfl_xor(lsum[m], 32);
      float inv[4];
#pragma unroll
      for (int reg = 0; reg < 4; ++reg)
        inv[reg] = 1.f / __shfl(lsum[m], g * 4 + reg);
#pragma unroll
      for (int reg = 0; reg < 4; ++reg) {
        int qrow = qr0 + m * 16 + g * 4 + reg;
        if (qrow < NQb) {
          u16* dst = Ob0 + (size_t)qrow * CC;
#pragma unroll
          for (int n = 0; n < 4; ++n)
            dst[n * 16 + ql] = f2bf(oacc[m][n][reg] * inv[reg]);
        }
      }
    }
  }
}

// ---------------------------------------------------------------------------
extern "C" void kernel_launch(void* const* d_in, const int* in_sizes, int n_in,
                              void* d_out, int out_size, void* d_ws,
                              size_t ws_size, hipStream_t stream) {
  const float* x      = (const float*)d_in[0];
  const float* enc    = (const float*)d_in[1];
  const float* q_w    = (const float*)d_in[2];
  const float* q_b    = (const float*)d_in[3];
  const float* kv_w   = (const float*)d_in[4];
  const float* kv_b   = (const float*)d_in[5];
  const float* proj_w = (const float*)d_in[6];
  const float* proj_b = (const float*)d_in[7];
  const float* qn_w   = (const float*)d_in[8];
  const float* qn_b   = (const float*)d_in[9];
  const float* kn_w   = (const float*)d_in[10];
  const float* kn_b   = (const float*)d_in[11];
  float* out = (float*)d_out;

  u16* ws = (u16*)d_ws;
  size_t off = 0;
  u16* Xbf  = ws + off; off += (size_t)MTOT * CC;   // also reused as O
  u16* Qbf  = ws + off; off += (size_t)MTOT * CC;
  u16* Ebf  = ws + off; off += (size_t)BB * NAk * CE;
  u16* QWb  = ws + off; off += (size_t)CC * CC;
  u16* KVWb = ws + off; off += (size_t)2 * CC * CE;
  u16* PWb  = ws + off; off += (size_t)CC * CC;
  u16* Kbf  = ws + off; off += (size_t)BB * HH * NAk * DD;
  u16* Vtbf = ws + off; off += (size_t)BB * HH * NAk * DD;

  auto cvt = [&](const float* s, u16* d, size_t n) {
    int n4 = (int)(n / 4);
    conv_f2b<<<(n4 + 255) / 256, 256, 0, stream>>>(s, d, n4);
  };
  cvt(x, Xbf, (size_t)MTOT * CC);
  cvt(enc, Ebf, (size_t)BB * NAk * CE);
  cvt(q_w, QWb, (size_t)CC * CC);
  cvt(kv_w, KVWb, (size_t)2 * CC * CE);
  cvt(proj_w, PWb, (size_t)CC * CC);

  gemm_bf16<CC, 0, 8><<<dim3(8, MTOT / 128), 256, 0, stream>>>(
      Xbf, QWb, q_b, qn_w, qn_b, Qbf, nullptr, nullptr);
  gemm_bf16<CE, 1, 16><<<dim3(16, (BB * NAk) / 128), 256, 0, stream>>>(
      Ebf, KVWb, kv_b, kn_w, kn_b, Kbf, Vtbf, nullptr);
  attn_mfma<<<dim3(HH, BB), 768, 0, stream>>>(Qbf, Kbf, Vtbf, Xbf);
  gemm_bf16<CC, 2, 8><<<dim3(8, MTOT / 128), 256, 0, stream>>>(
      Xbf, PWb, proj_b, nullptr, nullptr, nullptr, nullptr, out);
}

// Round 6
// 273.824 us; speedup vs baseline: 1.2993x; 1.0029x over previous
//
#include <hip/hip_runtime.h>
#include <hip/hip_bf16.h>

// Problem constants (fixed by setup_inputs)
#define BB   16      // batches (N_t)
#define NQb  1560    // q rows per batch
#define CC   1024    // channels
#define HH   16      // heads
#define DD   64      // head dim
#define NAk  256     // keys per batch
#define CE   768     // encoder channels
#define MTOT (BB*NQb) // 24960
#define NTIL ((NQb + 31) / 32)  // 49 q-tiles of 32 rows

// 0.125 (D^-0.5) * log2(e): folded into Q-LN so softmax is exp2(s) directly.
// |s| <= 64*0.1803 = 11.54 (Cauchy-Schwarz on unit-variance LN outputs).
#define QSCALE 0.18033688011112042f

typedef __attribute__((ext_vector_type(8))) short bf16x8;
typedef __attribute__((ext_vector_type(4))) float f32x4;
typedef unsigned short u16;
typedef unsigned int u32;

__device__ __forceinline__ u16 f2bf(float f) {  // RNE fp32->bf16
  unsigned u = __builtin_bit_cast(unsigned, f);
  u += 0x7FFFu + ((u >> 16) & 1u);
  return (u16)(u >> 16);
}

__device__ __forceinline__ u32 cvtpk(float a, float b) {  // 2xf32 -> packed bf16
  u32 r;
  asm("v_cvt_pk_bf16_f32 %0, %1, %2" : "=v"(r) : "v"(a), "v"(b));
  return r;
}

__device__ __forceinline__ void gl2lds16(const void* g, void* l) {
  __builtin_amdgcn_global_load_lds(
      (const __attribute__((address_space(1))) void*)g,
      (__attribute__((address_space(3))) void*)l, 16, 0, 0);
}

__device__ __forceinline__ f32x4 mfma16(bf16x8 a, bf16x8 b, f32x4 c) {
  return __builtin_amdgcn_mfma_f32_16x16x32_bf16(a, b, c, 0, 0, 0);
}

// ---------------------------------------------------------------------------
// fp32 -> bf16 bulk convert
// ---------------------------------------------------------------------------
__global__ __launch_bounds__(256) void conv_f2b(const float* __restrict__ s,
                                                u16* __restrict__ d, int n4) {
  int i = blockIdx.x * 256 + threadIdx.x;
  if (i >= n4) return;
  float4 v = reinterpret_cast<const float4*>(s)[i];
  ushort4 o;
  o.x = f2bf(v.x); o.y = f2bf(v.y); o.z = f2bf(v.z); o.w = f2bf(v.w);
  reinterpret_cast<ushort4*>(d)[i] = o;
}

// ---------------------------------------------------------------------------
// bf16 MFMA GEMM v2: out = A[M,KD] @ W[N,KD]^T (+bias, + epilogue)
// 256x128 tile, BK=64, 8 waves (4x2), 512 threads.
// TRIPLE-buffered LDS (144KB) + counted vmcnt(6): STAGE(t+2) issued before
// compute(t); per-tile wait is vmcnt(6) (tile t+1's 6 loads done, t+2's
// stay in flight) + raw s_barrier — vmcnt never drains to 0 in the loop.
// XOR-swizzled LDS (conflict-free, verified 0 in R5). T1 XCD swizzle.
// A-row staging clamped to MROWS-1 (M-tail); stores guarded by MROWS.
// EPI: 0 = per-head LN (eps 1e-6), scaled by QSCALE -> bf16 o_bf [M,CC]
//      1 = KV: cols<CC LN (eps 1e-5) -> Kbf[b][h][na][d]; cols>=CC ->
//          Vt[b][h][d][na] (both bf16)
//      2 = bias -> fp32 o_f [M,CC]
// ---------------------------------------------------------------------------
template <int KD, int EPI, int NXT, int MROWS>
__global__ __launch_bounds__(512, 2) void gemm_bf16(
    const u16* __restrict__ A, const u16* __restrict__ W,
    const float* __restrict__ bias, const float* __restrict__ lnw,
    const float* __restrict__ lnb, u16* __restrict__ o_bf,
    u16* __restrict__ o_bf2, float* __restrict__ o_f) {
  __shared__ u16 LDS[3][24576];  // per buf: A 256x64 (16384) | B 128x64 (8192)
  const int tid = threadIdx.x;
  const int l = tid & 63, wid = tid >> 6;   // 8 waves
  const int wr = wid >> 1, wc = wid & 1;    // wave -> 64-row x 64-col subtile
  const int g = l >> 4, ql = l & 15;

  // T1 bijective XCD swizzle (nwg % 8 == 0 for all instantiations)
  const int orig = (int)blockIdx.x + NXT * (int)blockIdx.y;
  const int q8 = (NXT * (int)gridDim.y) >> 3;
  const int nid = (orig & 7) * q8 + (orig >> 3);
  const int row0 = (nid / NXT) * 256, col0 = (nid % NXT) * 128;

  // staging geometry: 512 thr x 16B = 8KB per issue; A 4 issues, B 2 issues
  const int rb8 = tid >> 3;  // 0..63 (row within 64-row issue stripe)
  const int sc = ((((tid & 7) * 16) ^ ((rb8 & 7) << 4)) >> 1);  // elems
  const u16* Ab = A + sc;
  const u16* Bb = W + (size_t)(col0 + rb8) * KD + sc;

  f32x4 acc[4][4];
#pragma unroll
  for (int m = 0; m < 4; ++m)
#pragma unroll
    for (int n = 0; n < 4; ++n) acc[m][n] = (f32x4){0.f, 0.f, 0.f, 0.f};

  auto STAGE = [&](int buf, int t) {
    const int k0 = t * 64;
    char* lA = (char*)&LDS[buf][0] + tid * 16;
    char* lB = (char*)&LDS[buf][16384] + tid * 16;
#pragma unroll
    for (int j = 0; j < 4; ++j) {
      int r = row0 + j * 64 + rb8;
      r = min(r, MROWS - 1);  // M-tail clamp (dest-row swizzle preserved)
      gl2lds16(Ab + (size_t)r * KD + k0, lA + j * 8192);
    }
#pragma unroll
    for (int j = 0; j < 2; ++j)
      gl2lds16(Bb + (size_t)(j * 64) * KD + k0, lB + j * 8192);
  };

  auto COMPUTE = [&](int buf) {
    const char* As = (const char*)&LDS[buf][0];
    const char* Bs = (const char*)&LDS[buf][16384];
    bf16x8 af[4][2], bfv[4][2];
#pragma unroll
    for (int m = 0; m < 4; ++m) {
      int ra = wr * 64 + m * 16 + ql;
      int rx = (ra & 7) << 4;
#pragma unroll
      for (int kk = 0; kk < 2; ++kk)
        af[m][kk] = *(const bf16x8*)(As + ra * 128 + ((g * 16 + kk * 64) ^ rx));
    }
#pragma unroll
    for (int n = 0; n < 4; ++n) {
      int rb = wc * 64 + n * 16 + ql;
      int rx = (rb & 7) << 4;
#pragma unroll
      for (int kk = 0; kk < 2; ++kk)
        bfv[n][kk] = *(const bf16x8*)(Bs + rb * 128 + ((g * 16 + kk * 64) ^ rx));
    }
    __builtin_amdgcn_s_setprio(1);
#pragma unroll
    for (int kk = 0; kk < 2; ++kk)
#pragma unroll
      for (int m = 0; m < 4; ++m)
#pragma unroll
        for (int n = 0; n < 4; ++n)
          acc[m][n] = mfma16(af[m][kk], bfv[n][kk], acc[m][n]);
    __builtin_amdgcn_s_setprio(0);
  };

  constexpr int nt = KD / 64;
  STAGE(0, 0);
  STAGE(1, 1);
  asm volatile("s_waitcnt vmcnt(6)" ::: "memory");  // tile0 landed
  __builtin_amdgcn_s_barrier();
  __builtin_amdgcn_sched_barrier(0);
  for (int t = 0; t < nt - 2; ++t) {
    STAGE((t + 2) % 3, t + 2);
    COMPUTE(t % 3);
    asm volatile("s_waitcnt vmcnt(6)" ::: "memory");  // tile t+1 landed
    __builtin_amdgcn_s_barrier();
    __builtin_amdgcn_sched_barrier(0);
  }
  COMPUTE((nt - 2) % 3);
  asm volatile("s_waitcnt vmcnt(0)" ::: "memory");  // last tile landed
  __builtin_amdgcn_s_barrier();
  __builtin_amdgcn_sched_barrier(0);
  COMPUTE((nt - 1) % 3);

  const int colw = col0 + wc * 64;  // 64-aligned => one head for EPI 0/1
  float bv[4];
#pragma unroll
  for (int n = 0; n < 4; ++n) bv[n] = bias[colw + n * 16 + ql];

  if constexpr (EPI == 2) {
#pragma unroll
    for (int m = 0; m < 4; ++m)
#pragma unroll
      for (int reg = 0; reg < 4; ++reg) {
        int grow = row0 + wr * 64 + m * 16 + g * 4 + reg;
        if (grow < MROWS) {
#pragma unroll
          for (int n = 0; n < 4; ++n)
            o_f[(size_t)grow * CC + colw + n * 16 + ql] =
                acc[m][n][reg] + bv[n];
        }
      }
    return;
  }

  if constexpr (EPI == 0) {
    float lwv[4], lbv[4];
#pragma unroll
    for (int n = 0; n < 4; ++n) {
      lwv[n] = lnw[n * 16 + ql] * QSCALE;
      lbv[n] = lnb[n * 16 + ql] * QSCALE;
    }
    const int head = colw >> 6;
#pragma unroll
    for (int m = 0; m < 4; ++m)
#pragma unroll
      for (int reg = 0; reg < 4; ++reg) {
        float tv[4], s = 0.f, ss = 0.f;
#pragma unroll
        for (int n = 0; n < 4; ++n) {
          tv[n] = acc[m][n][reg] + bv[n];
          s += tv[n]; ss += tv[n] * tv[n];
        }
#pragma unroll
        for (int off = 1; off < 16; off <<= 1) {
          s  += __shfl_xor(s, off, 16);
          ss += __shfl_xor(ss, off, 16);
        }
        float mean = s * (1.f / 64.f);
        float var  = ss * (1.f / 64.f) - mean * mean;
        float rs   = rsqrtf(var + 1e-6f);
        int grow = row0 + wr * 64 + m * 16 + g * 4 + reg;
        if (grow < MROWS) {
          u16* dst = o_bf + (size_t)grow * CC + head * 64;
#pragma unroll
          for (int n = 0; n < 4; ++n)
            dst[n * 16 + ql] = f2bf((tv[n] - mean) * rs * lwv[n] + lbv[n]);
        }
      }
    return;
  }

  if constexpr (EPI == 1) {
    const bool isK = (colw < CC);
    const int head = (isK ? colw : (colw - CC)) >> 6;
    if (isK) {
      float lwv[4], lbv[4];
#pragma unroll
      for (int n = 0; n < 4; ++n) {
        lwv[n] = lnw[n * 16 + ql];
        lbv[n] = lnb[n * 16 + ql];
      }
#pragma unroll
      for (int m = 0; m < 4; ++m)
#pragma unroll
        for (int reg = 0; reg < 4; ++reg) {
          float tv[4], s = 0.f, ss = 0.f;
#pragma unroll
          for (int n = 0; n < 4; ++n) {
            tv[n] = acc[m][n][reg] + bv[n];
            s += tv[n]; ss += tv[n] * tv[n];
          }
#pragma unroll
          for (int off = 1; off < 16; off <<= 1) {
            s  += __shfl_xor(s, off, 16);
            ss += __shfl_xor(ss, off, 16);
          }
          float mean = s * (1.f / 64.f);
          float var  = ss * (1.f / 64.f) - mean * mean;
          float rs   = rsqrtf(var + 1e-5f);
          int grow = row0 + wr * 64 + m * 16 + g * 4 + reg;
          int bb = grow >> 8, na = grow & 255;
          u16* dst = o_bf + (size_t)((bb * HH + head) * NAk + na) * DD;
#pragma unroll
          for (int n = 0; n < 4; ++n)
            dst[n * 16 + ql] = f2bf((tv[n] - mean) * rs * lwv[n] + lbv[n]);
        }
    } else {
#pragma unroll
      for (int m = 0; m < 4; ++m)
#pragma unroll
        for (int reg = 0; reg < 4; ++reg) {
          int grow = row0 + wr * 64 + m * 16 + g * 4 + reg;
          int bb = grow >> 8, na = grow & 255;
          u16* dst = o_bf2 + (size_t)(bb * HH + head) * DD * NAk + na;
#pragma unroll
          for (int n = 0; n < 4; ++n) {
            int d = n * 16 + ql;
            dst[(size_t)d * NAk] = f2bf(acc[m][n][reg] + bv[n]);
          }
        }
    }
    return;
  }
}

// ---------------------------------------------------------------------------
// MFMA attention (R5, unchanged): PERSISTENT per-(b,h) block. grid=(HH,BB),
// 768 threads = 12 waves. K + Vt staged once into swizzled LDS, waves sweep
// 32-row q-tiles; swapped QK^T, NO-MAX softmax, cvt_pk P pack, deferred 1/l.
// ---------------------------------------------------------------------------
__global__ __launch_bounds__(768) void attn_mfma(
    const u16* __restrict__ Qbf, const u16* __restrict__ Kbf,
    const u16* __restrict__ Vtbf, u16* __restrict__ Obf) {
  __shared__ u16 Ks[256 * 64];    // 32KB [key][d], row-XOR swizzled
  __shared__ u16 Vts[64 * 256];   // 32KB [d][key], row-XOR swizzled
  __shared__ u16 P[12][32][64];   // 48KB per-wave [32 q][64 keys]
  const int tid = threadIdx.x, l = tid & 63, wid = tid >> 6;
  const int g = l >> 4, ql = l & 15;
  const int h = blockIdx.x, b = blockIdx.y;
  const size_t kvbase = (size_t)(b * HH + h) * (NAk * DD);
  const u16* Kp = Kbf + kvbase;
  const u16* Vp = Vtbf + kvbase;
  char* Pw = (char*)&P[wid][0][0];
  const int swz = (ql & 7) << 4;

  for (int idx = tid; idx < 4096; idx += 768) {
    if (idx < 2048) {
      int kr = idx >> 3, kc = idx & 7;
      gl2lds16(Kp + kr * 64 + (((kc * 16) ^ ((kr & 7) << 4)) >> 1),
               (char*)Ks + idx * 16);
    } else {
      int j = idx - 2048;
      int vr = j >> 5, vc = j & 31;
      gl2lds16(Vp + vr * 256 + (((vc * 16) ^ ((vr & 7) << 4)) >> 1),
               (char*)Vts + j * 16);
    }
  }
  __syncthreads();

  const u16* Qb0 = Qbf + (size_t)b * NQb * CC + h * DD;
  u16* Ob0 = Obf + (size_t)b * NQb * CC + h * DD;

  for (int t = wid; t < NTIL; t += 12) {
    const int qr0 = t * 32;
    bf16x8 qf[2][2];
#pragma unroll
    for (int m = 0; m < 2; ++m) {
      int qrow = min(qr0 + m * 16 + ql, NQb - 1);
      const u16* p = Qb0 + (size_t)qrow * CC + g * 8;
      qf[m][0] = *(const bf16x8*)(p);
      qf[m][1] = *(const bf16x8*)(p + 32);
    }

    f32x4 oacc[2][4];
#pragma unroll
    for (int m = 0; m < 2; ++m)
#pragma unroll
      for (int n = 0; n < 4; ++n) oacc[m][n] = (f32x4){0.f, 0.f, 0.f, 0.f};
    float lsum[2] = {0.f, 0.f};

#pragma unroll
    for (int c = 0; c < 4; ++c) {
      f32x4 sf[2][4];
#pragma unroll
      for (int m = 0; m < 2; ++m)
#pragma unroll
        for (int n = 0; n < 4; ++n) sf[m][n] = (f32x4){0.f, 0.f, 0.f, 0.f};
      __builtin_amdgcn_s_setprio(1);
#pragma unroll
      for (int n = 0; n < 4; ++n) {
        const char* kbase = (const char*)Ks + (c * 64 + n * 16 + ql) * 128;
        bf16x8 ka0 = *(const bf16x8*)(kbase + ((g * 16) ^ swz));
        bf16x8 ka1 = *(const bf16x8*)(kbase + ((g * 16 + 64) ^ swz));
        sf[0][n] = mfma16(ka0, qf[0][0], sf[0][n]);
        sf[0][n] = mfma16(ka1, qf[0][1], sf[0][n]);
        sf[1][n] = mfma16(ka0, qf[1][0], sf[1][n]);
        sf[1][n] = mfma16(ka1, qf[1][1], sf[1][n]);
      }
      __builtin_amdgcn_s_setprio(0);

#pragma unroll
      for (int m = 0; m < 2; ++m) {
        float cs = 0.f;
#pragma unroll
        for (int n = 0; n < 4; ++n)
#pragma unroll
          for (int reg = 0; reg < 4; ++reg) {
            float e = exp2f(sf[m][n][reg]);
            sf[m][n][reg] = e;
            cs += e;
          }
        lsum[m] += cs;
        char* rowp = Pw + (m * 16 + ql) * 128;
#pragma unroll
        for (int n = 0; n < 4; ++n) {
          u32 w0 = cvtpk(sf[m][n][0], sf[m][n][1]);
          u32 w1 = cvtpk(sf[m][n][2], sf[m][n][3]);
          *(uint2*)(rowp + ((n * 32 + g * 8) ^ swz)) = make_uint2(w0, w1);
        }
      }

      __builtin_amdgcn_s_setprio(1);
#pragma unroll
      for (int ks = 0; ks < 2; ++ks) {
        bf16x8 pa[2], vb[4];
#pragma unroll
        for (int m = 0; m < 2; ++m)
          pa[m] = *(const bf16x8*)(Pw + (m * 16 + ql) * 128 +
                                   ((ks * 64 + g * 16) ^ swz));
#pragma unroll
        for (int n = 0; n < 4; ++n)
          vb[n] = *(const bf16x8*)((const char*)Vts + (n * 16 + ql) * 512 +
                                   ((c * 128 + ks * 64 + g * 16) ^ swz));
#pragma unroll
        for (int m = 0; m < 2; ++m)
#pragma unroll
          for (int n = 0; n < 4; ++n)
            oacc[m][n] = mfma16(pa[m], vb[n], oacc[m][n]);
      }
      __builtin_amdgcn_s_setprio(0);
    }

#pragma unroll
    for (int m = 0; m < 2; ++m) {
      lsum[m] += __shfl_xor(lsum[m], 16);
      lsum[m] += __shfl_xor(lsum[m], 32);
      float inv[4];
#pragma unroll
      for (int reg = 0; reg < 4; ++reg)
        inv[reg] = 1.f / __shfl(lsum[m], g * 4 + reg);
#pragma unroll
      for (int reg = 0; reg < 4; ++reg) {
        int qrow = qr0 + m * 16 + g * 4 + reg;
        if (qrow < NQb) {
          u16* dst = Ob0 + (size_t)qrow * CC;
#pragma unroll
          for (int n = 0; n < 4; ++n)
            dst[n * 16 + ql] = f2bf(oacc[m][n][reg] * inv[reg]);
        }
      }
    }
  }
}

// ---------------------------------------------------------------------------
extern "C" void kernel_launch(void* const* d_in, const int* in_sizes, int n_in,
                              void* d_out, int out_size, void* d_ws,
                              size_t ws_size, hipStream_t stream) {
  const float* x      = (const float*)d_in[0];
  const float* enc    = (const float*)d_in[1];
  const float* q_w    = (const float*)d_in[2];
  const float* q_b    = (const float*)d_in[3];
  const float* kv_w   = (const float*)d_in[4];
  const float* kv_b   = (const float*)d_in[5];
  const float* proj_w = (const float*)d_in[6];
  const float* proj_b = (const float*)d_in[7];
  const float* qn_w   = (const float*)d_in[8];
  const float* qn_b   = (const float*)d_in[9];
  const float* kn_w   = (const float*)d_in[10];
  const float* kn_b   = (const float*)d_in[11];
  float* out = (float*)d_out;

  u16* ws = (u16*)d_ws;
  size_t off = 0;
  u16* Xbf  = ws + off; off += (size_t)MTOT * CC;   // also reused as O
  u16* Qbf  = ws + off; off += (size_t)MTOT * CC;
  u16* Ebf  = ws + off; off += (size_t)BB * NAk * CE;
  u16* QWb  = ws + off; off += (size_t)CC * CC;
  u16* KVWb = ws + off; off += (size_t)2 * CC * CE;
  u16* PWb  = ws + off; off += (size_t)CC * CC;
  u16* Kbf  = ws + off; off += (size_t)BB * HH * NAk * DD;
  u16* Vtbf = ws + off; off += (size_t)BB * HH * NAk * DD;

  auto cvt = [&](const float* s, u16* d, size_t n) {
    int n4 = (int)(n / 4);
    conv_f2b<<<(n4 + 255) / 256, 256, 0, stream>>>(s, d, n4);
  };
  cvt(x, Xbf, (size_t)MTOT * CC);
  cvt(enc, Ebf, (size_t)BB * NAk * CE);
  cvt(q_w, QWb, (size_t)CC * CC);
  cvt(kv_w, KVWb, (size_t)2 * CC * CE);
  cvt(proj_w, PWb, (size_t)CC * CC);

  // 256-row x 128-col tiles; grid.x = col tiles, grid.y = row tiles
  gemm_bf16<CC, 0, 8, MTOT><<<dim3(8, 98), 512, 0, stream>>>(
      Xbf, QWb, q_b, qn_w, qn_b, Qbf, nullptr, nullptr);
  gemm_bf16<CE, 1, 16, BB * NAk><<<dim3(16, 16), 512, 0, stream>>>(
      Ebf, KVWb, kv_b, kn_w, kn_b, Kbf, Vtbf, nullptr);
  attn_mfma<<<dim3(HH, BB), 768, 0, stream>>>(Qbf, Kbf, Vtbf, Xbf);
  gemm_bf16<CC, 2, 8, MTOT><<<dim3(8, 98), 512, 0, stream>>>(
      Xbf, PWb, proj_b, nullptr, nullptr, nullptr, nullptr, out);
}

// Round 7
// 264.504 us; speedup vs baseline: 1.3451x; 1.0352x over previous
//
#include <hip/hip_runtime.h>
#include <hip/hip_bf16.h>

// Problem constants (fixed by setup_inputs)
#define BB   16      // batches (N_t)
#define NQb  1560    // q rows per batch
#define CC   1024    // channels
#define HH   16      // heads
#define DD   64      // head dim
#define NAk  256     // keys per batch
#define CE   768     // encoder channels
#define MTOT (BB*NQb) // 24960
#define NTIL ((NQb + 31) / 32)  // 49 q-tiles of 32 rows

// 0.125 (D^-0.5) * log2(e): folded into Q-LN so softmax is exp2(s) directly.
// |s| <= 64*0.1803 = 11.54 (Cauchy-Schwarz on unit-variance LN outputs).
#define QSCALE 0.18033688011112042f

typedef __attribute__((ext_vector_type(8))) short bf16x8;
typedef __attribute__((ext_vector_type(4))) float f32x4;
typedef unsigned short u16;
typedef unsigned int u32;

__device__ __forceinline__ u16 f2bf(float f) {  // RNE fp32->bf16
  unsigned u = __builtin_bit_cast(unsigned, f);
  u += 0x7FFFu + ((u >> 16) & 1u);
  return (u16)(u >> 16);
}

__device__ __forceinline__ u32 cvtpk(float a, float b) {  // 2xf32 -> packed bf16
  u32 r;
  asm("v_cvt_pk_bf16_f32 %0, %1, %2" : "=v"(r) : "v"(a), "v"(b));
  return r;
}

__device__ __forceinline__ void gl2lds16(const void* g, void* l) {
  __builtin_amdgcn_global_load_lds(
      (const __attribute__((address_space(1))) void*)g,
      (__attribute__((address_space(3))) void*)l, 16, 0, 0);
}

__device__ __forceinline__ f32x4 mfma16(bf16x8 a, bf16x8 b, f32x4 c) {
  return __builtin_amdgcn_mfma_f32_16x16x32_bf16(a, b, c, 0, 0, 0);
}

// ---------------------------------------------------------------------------
// fp32 -> bf16 bulk convert
// ---------------------------------------------------------------------------
__global__ __launch_bounds__(256) void conv_f2b(const float* __restrict__ s,
                                                u16* __restrict__ d, int n4) {
  int i = blockIdx.x * 256 + threadIdx.x;
  if (i >= n4) return;
  float4 v = reinterpret_cast<const float4*>(s)[i];
  ushort4 o;
  o.x = f2bf(v.x); o.y = f2bf(v.y); o.z = f2bf(v.z); o.w = f2bf(v.w);
  reinterpret_cast<ushort4*>(d)[i] = o;
}

// ---------------------------------------------------------------------------
// 8-phase bf16 MFMA GEMM (m201-style): out = A[M,KD] @ W[N,KD]^T (+epilogue)
// 256x256 tile, BK=64, 8 waves (4M x 2N: wave = 64 rows x 128 cols), 512 thr.
// LDS 128KB: A = 2 bufs x (2 halves x 128rows x 64cols bf16); B same.
// Per K-tile 4 phases: {ds_read subtile; stage 1 half-tile (2 gl2lds);
// s_barrier; lgkmcnt(0)+sched_barrier; setprio(1); 16 MFMA; setprio(0);
// s_barrier}. Stage order at tile t: ph0->(t+1,B1), ph1->(t+2,A0),
// ph2->(t+2,A1), ph3->(t+2,B0); vmcnt(6) once per tile (3 halves in flight).
// Slot discipline (reads of buf b vs (t+2)-stages into buf b):
//   A-half0 read ph0 < staged ph1; A-half1 read ph0 < ph2;
//   B-half0 last read ph2 (wc0 pulls n4-7/kk1 reads into ph2) < ph3.
// EPI: 0 = per-head LN (eps 1e-6) * QSCALE -> bf16; 1 = KV (K: LN eps 1e-5 ->
// Kbf[b][h][na][d]; V -> Vt[b][h][d][na]); 2 = bias -> fp32.
// ---------------------------------------------------------------------------
template <int KD, int EPI, int NXT, int MROWS>
__global__ __launch_bounds__(512, 2) void gemm8p(
    const u16* __restrict__ A, const u16* __restrict__ W,
    const float* __restrict__ bias, const float* __restrict__ lnw,
    const float* __restrict__ lnb, u16* __restrict__ o_bf,
    u16* __restrict__ o_bf2, float* __restrict__ o_f) {
  __shared__ u16 LDS[65536];  // 128KB. A: [0,64KB) = 2 bufs; B: [64KB,128KB)
  constexpr int nt = KD / 64;
  const int tid = threadIdx.x;
  const int l = tid & 63, wid = tid >> 6;
  const int wr = wid >> 1, wc = wid & 1;  // 4M x 2N wave grid
  const int g = l >> 4, ql = l & 15;
  const int swz = (ql & 7) << 4;

  // T1 bijective XCD swizzle (nwg % 8 == 0 in all instantiations)
  const int orig = (int)blockIdx.x + NXT * (int)blockIdx.y;
  const int q8 = (NXT * (int)gridDim.y) >> 3;
  const int nid = (orig & 7) * q8 + (orig >> 3);
  const int row0 = (nid / NXT) * 256, col0 = (nid % NXT) * 256;

  // staging geometry: one half-tile = 128 rows x 128B, 2 issues of 8KB
  const int rb = tid >> 3;   // 0..63 row within issue stripe
  const int c8 = tid & 7;    // 16B chunk within 128B row
  const int swsrc = ((c8 * 16) ^ ((rb & 7) << 4)) >> 1;  // elems

  auto STAGE_A = [&](int tt, int hh) {
    const int k0 = min(tt, nt - 1) * 64;
    char* ldst = (char*)LDS + (tt & 1) * 32768 + hh * 16384 + tid * 16;
    const u16* src = A + k0 + swsrc;
#pragma unroll
    for (int j = 0; j < 2; ++j) {
      int r = row0 + hh * 128 + j * 64 + rb;
      r = min(r, MROWS - 1);
      gl2lds16(src + (size_t)r * KD, ldst + j * 8192);
    }
  };
  auto STAGE_B = [&](int tt, int hh) {
    const int k0 = min(tt, nt - 1) * 64;
    char* ldst =
        (char*)LDS + 65536 + (tt & 1) * 32768 + hh * 16384 + tid * 16;
    const u16* src = W + (size_t)(col0 + hh * 128) * KD + k0 + swsrc;
#pragma unroll
    for (int j = 0; j < 2; ++j)
      gl2lds16(src + (size_t)(j * 64 + rb) * KD, ldst + j * 8192);
  };

  f32x4 acc[4][8];
#pragma unroll
  for (int m = 0; m < 4; ++m)
#pragma unroll
    for (int n = 0; n < 8; ++n) acc[m][n] = (f32x4){0.f, 0.f, 0.f, 0.f};
  bf16x8 af[4][2], bfr[8][2];

  // prologue: 7 halves (14 loads); vmcnt(6) => tile0's 4 halves landed
  STAGE_A(0, 0); STAGE_A(0, 1); STAGE_B(0, 0); STAGE_B(0, 1);
  STAGE_A(1, 0); STAGE_A(1, 1); STAGE_B(1, 0);
  asm volatile("s_waitcnt vmcnt(6)" ::: "memory");
  __builtin_amdgcn_s_barrier();

  for (int t = 0; t < nt; ++t) {
    const char* Ab_ = (const char*)LDS + (t & 1) * 32768;
    const char* Bb_ = (const char*)LDS + 65536 + (t & 1) * 32768;
    auto RDA = [&](int m) {
      const char* p =
          Ab_ + (wr >> 1) * 16384 + ((wr & 1) * 64 + m * 16 + ql) * 128;
      af[m][0] = *(const bf16x8*)(p + ((g * 16) ^ swz));
      af[m][1] = *(const bf16x8*)(p + ((g * 16 + 64) ^ swz));
    };
    auto RDB = [&](int n, int kk) {
      const char* p = Bb_ + wc * 16384 + (n * 16 + ql) * 128;
      bfr[n][kk] = *(const bf16x8*)(p + ((g * 16 + kk * 64) ^ swz));
    };
    auto MFMAQ = [&](int nq, int kk) {
      __builtin_amdgcn_s_setprio(1);
#pragma unroll
      for (int m = 0; m < 4; ++m)
#pragma unroll
        for (int j = 0; j < 4; ++j)
          acc[m][nq + j] = mfma16(af[m][kk], bfr[nq + j][kk], acc[m][nq + j]);
      __builtin_amdgcn_s_setprio(0);
    };

    // ---- phase 0: read A(all) + B[n0-3,k0]; stage (t+1,B1)
    RDA(0); RDA(1); RDA(2); RDA(3);
    RDB(0, 0); RDB(1, 0); RDB(2, 0); RDB(3, 0);
    STAGE_B(t + 1, 1);
    __builtin_amdgcn_s_barrier();
    asm volatile("s_waitcnt lgkmcnt(0)" ::: "memory");
    __builtin_amdgcn_sched_barrier(0);
    MFMAQ(0, 0);
    __builtin_amdgcn_s_barrier();

    // ---- phase 1: read B[n4-7,k0]; stage (t+2,A0)
    RDB(4, 0); RDB(5, 0); RDB(6, 0); RDB(7, 0);
    STAGE_A(t + 2, 0);
    __builtin_amdgcn_s_barrier();
    asm volatile("s_waitcnt lgkmcnt(0)" ::: "memory");
    __builtin_amdgcn_sched_barrier(0);
    MFMAQ(4, 0);
    __builtin_amdgcn_s_barrier();

    // ---- phase 2: read B[n0-3,k1] (+ wc0: B[n4-7,k1]); stage (t+2,A1)
    RDB(0, 1); RDB(1, 1); RDB(2, 1); RDB(3, 1);
    if (wc == 0) { RDB(4, 1); RDB(5, 1); RDB(6, 1); RDB(7, 1); }
    STAGE_A(t + 2, 1);
    __builtin_amdgcn_s_barrier();
    asm volatile("s_waitcnt lgkmcnt(0)" ::: "memory");
    __builtin_amdgcn_sched_barrier(0);
    MFMAQ(0, 1);
    __builtin_amdgcn_s_barrier();

    // ---- phase 3: (wc1: read B[n4-7,k1]); stage (t+2,B0); vmcnt(6)
    if (wc == 1) { RDB(4, 1); RDB(5, 1); RDB(6, 1); RDB(7, 1); }
    STAGE_B(t + 2, 0);
    asm volatile("s_waitcnt vmcnt(6)" ::: "memory");  // tile t+1 landed
    __builtin_amdgcn_s_barrier();
    asm volatile("s_waitcnt lgkmcnt(0)" ::: "memory");
    __builtin_amdgcn_sched_barrier(0);
    MFMAQ(4, 1);
    __builtin_amdgcn_s_barrier();
  }

  // ---------------- epilogue ----------------
  const int colw = col0 + wc * 128;
  float bv[8];
#pragma unroll
  for (int n = 0; n < 8; ++n) bv[n] = bias[colw + n * 16 + ql];

  if constexpr (EPI == 2) {
#pragma unroll
    for (int m = 0; m < 4; ++m)
#pragma unroll
      for (int reg = 0; reg < 4; ++reg) {
        int grow = row0 + wr * 64 + m * 16 + g * 4 + reg;
        if (grow < MROWS) {
#pragma unroll
          for (int n = 0; n < 8; ++n)
            o_f[(size_t)grow * CC + colw + n * 16 + ql] =
                acc[m][n][reg] + bv[n];
        }
      }
    return;
  }

  if constexpr (EPI == 0) {
    float lwv[4], lbv[4];
#pragma unroll
    for (int j = 0; j < 4; ++j) {
      lwv[j] = lnw[j * 16 + ql] * QSCALE;
      lbv[j] = lnb[j * 16 + ql] * QSCALE;
    }
    const int head0 = colw >> 6;
#pragma unroll
    for (int m = 0; m < 4; ++m)
#pragma unroll
      for (int reg = 0; reg < 4; ++reg) {
        int grow = row0 + wr * 64 + m * 16 + g * 4 + reg;
        if (grow < MROWS) {
#pragma unroll
          for (int nh = 0; nh < 2; ++nh) {
            float tv[4], s = 0.f, ss = 0.f;
#pragma unroll
            for (int j = 0; j < 4; ++j) {
              tv[j] = acc[m][nh * 4 + j][reg] + bv[nh * 4 + j];
              s += tv[j]; ss += tv[j] * tv[j];
            }
#pragma unroll
            for (int off = 1; off < 16; off <<= 1) {
              s  += __shfl_xor(s, off, 16);
              ss += __shfl_xor(ss, off, 16);
            }
            float mean = s * (1.f / 64.f);
            float var  = ss * (1.f / 64.f) - mean * mean;
            float rs   = rsqrtf(var + 1e-6f);
            u16* dst = o_bf + (size_t)grow * CC + (head0 + nh) * 64;
#pragma unroll
            for (int j = 0; j < 4; ++j)
              dst[j * 16 + ql] = f2bf((tv[j] - mean) * rs * lwv[j] + lbv[j]);
          }
        }
      }
    return;
  }

  if constexpr (EPI == 1) {
    const bool isK = (colw < CC);
    const int head0 = (isK ? colw : (colw - CC)) >> 6;
    if (isK) {
      float lwv[4], lbv[4];
#pragma unroll
      for (int j = 0; j < 4; ++j) {
        lwv[j] = lnw[j * 16 + ql];
        lbv[j] = lnb[j * 16 + ql];
      }
#pragma unroll
      for (int m = 0; m < 4; ++m)
#pragma unroll
        for (int reg = 0; reg < 4; ++reg) {
          int grow = row0 + wr * 64 + m * 16 + g * 4 + reg;
          int bb = grow >> 8, na = grow & 255;
#pragma unroll
          for (int nh = 0; nh < 2; ++nh) {
            float tv[4], s = 0.f, ss = 0.f;
#pragma unroll
            for (int j = 0; j < 4; ++j) {
              tv[j] = acc[m][nh * 4 + j][reg] + bv[nh * 4 + j];
              s += tv[j]; ss += tv[j] * tv[j];
            }
#pragma unroll
            for (int off = 1; off < 16; off <<= 1) {
              s  += __shfl_xor(s, off, 16);
              ss += __shfl_xor(ss, off, 16);
            }
            float mean = s * (1.f / 64.f);
            float var  = ss * (1.f / 64.f) - mean * mean;
            float rs   = rsqrtf(var + 1e-5f);
            u16* dst =
                o_bf + (size_t)((bb * HH + head0 + nh) * NAk + na) * DD;
#pragma unroll
            for (int j = 0; j < 4; ++j)
              dst[j * 16 + ql] = f2bf((tv[j] - mean) * rs * lwv[j] + lbv[j]);
          }
        }
    } else {
#pragma unroll
      for (int m = 0; m < 4; ++m)
#pragma unroll
        for (int reg = 0; reg < 4; ++reg) {
          int grow = row0 + wr * 64 + m * 16 + g * 4 + reg;
          int bb = grow >> 8, na = grow & 255;
#pragma unroll
          for (int nh = 0; nh < 2; ++nh) {
            u16* dst = o_bf2 + (size_t)(bb * HH + head0 + nh) * DD * NAk + na;
#pragma unroll
            for (int j = 0; j < 4; ++j) {
              int d = j * 16 + ql;
              dst[(size_t)d * NAk] =
                  f2bf(acc[m][nh * 4 + j][reg] + bv[nh * 4 + j]);
            }
          }
        }
    }
    return;
  }
}

// ---------------------------------------------------------------------------
// MFMA attention (R5/R6, unchanged): PERSISTENT per-(b,h) block. grid=(HH,BB),
// 768 threads = 12 waves. K + Vt staged once into swizzled LDS, waves sweep
// 32-row q-tiles; swapped QK^T, NO-MAX softmax, cvt_pk P pack, deferred 1/l.
// ---------------------------------------------------------------------------
__global__ __launch_bounds__(768) void attn_mfma(
    const u16* __restrict__ Qbf, const u16* __restrict__ Kbf,
    const u16* __restrict__ Vtbf, u16* __restrict__ Obf) {
  __shared__ u16 Ks[256 * 64];    // 32KB [key][d], row-XOR swizzled
  __shared__ u16 Vts[64 * 256];   // 32KB [d][key], row-XOR swizzled
  __shared__ u16 P[12][32][64];   // 48KB per-wave [32 q][64 keys]
  const int tid = threadIdx.x, l = tid & 63, wid = tid >> 6;
  const int g = l >> 4, ql = l & 15;
  const int h = blockIdx.x, b = blockIdx.y;
  const size_t kvbase = (size_t)(b * HH + h) * (NAk * DD);
  const u16* Kp = Kbf + kvbase;
  const u16* Vp = Vtbf + kvbase;
  char* Pw = (char*)&P[wid][0][0];
  const int swz = (ql & 7) << 4;

  for (int idx = tid; idx < 4096; idx += 768) {
    if (idx < 2048) {
      int kr = idx >> 3, kc = idx & 7;
      gl2lds16(Kp + kr * 64 + (((kc * 16) ^ ((kr & 7) << 4)) >> 1),
               (char*)Ks + idx * 16);
    } else {
      int j = idx - 2048;
      int vr = j >> 5, vc = j & 31;
      gl2lds16(Vp + vr * 256 + (((vc * 16) ^ ((vr & 7) << 4)) >> 1),
               (char*)Vts + j * 16);
    }
  }
  __syncthreads();

  const u16* Qb0 = Qbf + (size_t)b * NQb * CC + h * DD;
  u16* Ob0 = Obf + (size_t)b * NQb * CC + h * DD;

  for (int t = wid; t < NTIL; t += 12) {
    const int qr0 = t * 32;
    bf16x8 qf[2][2];
#pragma unroll
    for (int m = 0; m < 2; ++m) {
      int qrow = min(qr0 + m * 16 + ql, NQb - 1);
      const u16* p = Qb0 + (size_t)qrow * CC + g * 8;
      qf[m][0] = *(const bf16x8*)(p);
      qf[m][1] = *(const bf16x8*)(p + 32);
    }

    f32x4 oacc[2][4];
#pragma unroll
    for (int m = 0; m < 2; ++m)
#pragma unroll
      for (int n = 0; n < 4; ++n) oacc[m][n] = (f32x4){0.f, 0.f, 0.f, 0.f};
    float lsum[2] = {0.f, 0.f};

#pragma unroll
    for (int c = 0; c < 4; ++c) {
      f32x4 sf[2][4];
#pragma unroll
      for (int m = 0; m < 2; ++m)
#pragma unroll
        for (int n = 0; n < 4; ++n) sf[m][n] = (f32x4){0.f, 0.f, 0.f, 0.f};
      __builtin_amdgcn_s_setprio(1);
#pragma unroll
      for (int n = 0; n < 4; ++n) {
        const char* kbase = (const char*)Ks + (c * 64 + n * 16 + ql) * 128;
        bf16x8 ka0 = *(const bf16x8*)(kbase + ((g * 16) ^ swz));
        bf16x8 ka1 = *(const bf16x8*)(kbase + ((g * 16 + 64) ^ swz));
        sf[0][n] = mfma16(ka0, qf[0][0], sf[0][n]);
        sf[0][n] = mfma16(ka1, qf[0][1], sf[0][n]);
        sf[1][n] = mfma16(ka0, qf[1][0], sf[1][n]);
        sf[1][n] = mfma16(ka1, qf[1][1], sf[1][n]);
      }
      __builtin_amdgcn_s_setprio(0);

#pragma unroll
      for (int m = 0; m < 2; ++m) {
        float cs = 0.f;
#pragma unroll
        for (int n = 0; n < 4; ++n)
#pragma unroll
          for (int reg = 0; reg < 4; ++reg) {
            float e = exp2f(sf[m][n][reg]);
            sf[m][n][reg] = e;
            cs += e;
          }
        lsum[m] += cs;
        char* rowp = Pw + (m * 16 + ql) * 128;
#pragma unroll
        for (int n = 0; n < 4; ++n) {
          u32 w0 = cvtpk(sf[m][n][0], sf[m][n][1]);
          u32 w1 = cvtpk(sf[m][n][2], sf[m][n][3]);
          *(uint2*)(rowp + ((n * 32 + g * 8) ^ swz)) = make_uint2(w0, w1);
        }
      }

      __builtin_amdgcn_s_setprio(1);
#pragma unroll
      for (int ks = 0; ks < 2; ++ks) {
        bf16x8 pa[2], vb[4];
#pragma unroll
        for (int m = 0; m < 2; ++m)
          pa[m] = *(const bf16x8*)(Pw + (m * 16 + ql) * 128 +
                                   ((ks * 64 + g * 16) ^ swz));
#pragma unroll
        for (int n = 0; n < 4; ++n)
          vb[n] = *(const bf16x8*)((const char*)Vts + (n * 16 + ql) * 512 +
                                   ((c * 128 + ks * 64 + g * 16) ^ swz));
#pragma unroll
        for (int m = 0; m < 2; ++m)
#pragma unroll
          for (int n = 0; n < 4; ++n)
            oacc[m][n] = mfma16(pa[m], vb[n], oacc[m][n]);
      }
      __builtin_amdgcn_s_setprio(0);
    }

#pragma unroll
    for (int m = 0; m < 2; ++m) {
      lsum[m] += __shfl_xor(lsum[m], 16);
      lsum[m] += __shfl_xor(lsum[m], 32);
      float inv[4];
#pragma unroll
      for (int reg = 0; reg < 4; ++reg)
        inv[reg] = 1.f / __shfl(lsum[m], g * 4 + reg);
#pragma unroll
      for (int reg = 0; reg < 4; ++reg) {
        int qrow = qr0 + m * 16 + g * 4 + reg;
        if (qrow < NQb) {
          u16* dst = Ob0 + (size_t)qrow * CC;
#pragma unroll
          for (int n = 0; n < 4; ++n)
            dst[n * 16 + ql] = f2bf(oacc[m][n][reg] * inv[reg]);
        }
      }
    }
  }
}

// ---------------------------------------------------------------------------
extern "C" void kernel_launch(void* const* d_in, const int* in_sizes, int n_in,
                              void* d_out, int out_size, void* d_ws,
                              size_t ws_size, hipStream_t stream) {
  const float* x      = (const float*)d_in[0];
  const float* enc    = (const float*)d_in[1];
  const float* q_w    = (const float*)d_in[2];
  const float* q_b    = (const float*)d_in[3];
  const float* kv_w   = (const float*)d_in[4];
  const float* kv_b   = (const float*)d_in[5];
  const float* proj_w = (const float*)d_in[6];
  const float* proj_b = (const float*)d_in[7];
  const float* qn_w   = (const float*)d_in[8];
  const float* qn_b   = (const float*)d_in[9];
  const float* kn_w   = (const float*)d_in[10];
  const float* kn_b   = (const float*)d_in[11];
  float* out = (float*)d_out;

  u16* ws = (u16*)d_ws;
  size_t off = 0;
  u16* Xbf  = ws + off; off += (size_t)MTOT * CC;   // also reused as O
  u16* Qbf  = ws + off; off += (size_t)MTOT * CC;
  u16* Ebf  = ws + off; off += (size_t)BB * NAk * CE;
  u16* QWb  = ws + off; off += (size_t)CC * CC;
  u16* KVWb = ws + off; off += (size_t)2 * CC * CE;
  u16* PWb  = ws + off; off += (size_t)CC * CC;
  u16* Kbf  = ws + off; off += (size_t)BB * HH * NAk * DD;
  u16* Vtbf = ws + off; off += (size_t)BB * HH * NAk * DD;

  auto cvt = [&](const float* s, u16* d, size_t n) {
    int n4 = (int)(n / 4);
    conv_f2b<<<(n4 + 255) / 256, 256, 0, stream>>>(s, d, n4);
  };
  cvt(x, Xbf, (size_t)MTOT * CC);
  cvt(enc, Ebf, (size_t)BB * NAk * CE);
  cvt(q_w, QWb, (size_t)CC * CC);
  cvt(kv_w, KVWb, (size_t)2 * CC * CE);
  cvt(proj_w, PWb, (size_t)CC * CC);

  // 256x256 tiles; grid.x = col tiles, grid.y = row tiles
  gemm8p<CC, 0, 4, MTOT><<<dim3(4, 98), 512, 0, stream>>>(
      Xbf, QWb, q_b, qn_w, qn_b, Qbf, nullptr, nullptr);
  gemm8p<CE, 1, 8, BB * NAk><<<dim3(8, 16), 512, 0, stream>>>(
      Ebf, KVWb, kv_b, kn_w, kn_b, Kbf, Vtbf, nullptr);
  attn_mfma<<<dim3(HH, BB), 768, 0, stream>>>(Qbf, Kbf, Vtbf, Xbf);
  gemm8p<CC, 2, 4, MTOT><<<dim3(4, 98), 512, 0, stream>>>(
      Xbf, PWb, proj_b, nullptr, nullptr, nullptr, nullptr, out);
}

// Round 8
// 252.648 us; speedup vs baseline: 1.4082x; 1.0469x over previous
//
#include <hip/hip_runtime.h>
#include <hip/hip_bf16.h>

// Problem constants (fixed by setup_inputs)
#define BB   16      // batches (N_t)
#define NQb  1560    // q rows per batch
#define CC   1024    // channels
#define HH   16      // heads
#define DD   64      // head dim
#define NAk  256     // keys per batch
#define CE   768     // encoder channels
#define MTOT (BB*NQb) // 24960
#define NTIL ((NQb + 31) / 32)  // 49 q-tiles of 32 rows

// 0.125 (D^-0.5) * log2(e): folded into Q-LN so softmax is exp2(s) directly.
// |s| <= 64*0.1803 = 11.54 (Cauchy-Schwarz on unit-variance LN outputs).
#define QSCALE 0.18033688011112042f

typedef __attribute__((ext_vector_type(8))) short bf16x8;
typedef __attribute__((ext_vector_type(4))) float f32x4;
typedef unsigned short u16;
typedef unsigned int u32;

__device__ __forceinline__ u16 f2bf(float f) {  // RNE fp32->bf16
  unsigned u = __builtin_bit_cast(unsigned, f);
  u += 0x7FFFu + ((u >> 16) & 1u);
  return (u16)(u >> 16);
}

__device__ __forceinline__ u32 cvtpk(float a, float b) {  // 2xf32 -> packed bf16
  u32 r;
  asm("v_cvt_pk_bf16_f32 %0, %1, %2" : "=v"(r) : "v"(a), "v"(b));
  return r;
}

__device__ __forceinline__ void gl2lds16(const void* g, void* l) {
  __builtin_amdgcn_global_load_lds(
      (const __attribute__((address_space(1))) void*)g,
      (__attribute__((address_space(3))) void*)l, 16, 0, 0);
}

__device__ __forceinline__ f32x4 mfma16(bf16x8 a, bf16x8 b, f32x4 c) {
  return __builtin_amdgcn_mfma_f32_16x16x32_bf16(a, b, c, 0, 0, 0);
}

// ---------------------------------------------------------------------------
// Fused fp32 -> bf16 convert for ALL five inputs in ONE launch (segment table).
// Indices are in float4 units; e0..e4 are cumulative segment ends.
// ---------------------------------------------------------------------------
__global__ __launch_bounds__(256) void conv_all(
    const float* __restrict__ s0, const float* __restrict__ s1,
    const float* __restrict__ s2, const float* __restrict__ s3,
    const float* __restrict__ s4, u16* __restrict__ d0, u16* __restrict__ d1,
    u16* __restrict__ d2, u16* __restrict__ d3, u16* __restrict__ d4, int e0,
    int e1, int e2, int e3, int e4) {
  for (int i = blockIdx.x * 256 + threadIdx.x; i < e4; i += gridDim.x * 256) {
    const float* s; u16* d; int j;
    if (i < e0)      { s = s0; d = d0; j = i; }
    else if (i < e1) { s = s1; d = d1; j = i - e0; }
    else if (i < e2) { s = s2; d = d2; j = i - e1; }
    else if (i < e3) { s = s3; d = d3; j = i - e2; }
    else             { s = s4; d = d4; j = i - e3; }
    float4 v = reinterpret_cast<const float4*>(s)[j];
    ushort4 o;
    o.x = f2bf(v.x); o.y = f2bf(v.y); o.z = f2bf(v.z); o.w = f2bf(v.w);
    reinterpret_cast<ushort4*>(d)[j] = o;
  }
}

// ---------------------------------------------------------------------------
// bf16 MFMA GEMM v4 (m97-style, occupancy-first): out = A[M,KD]@W[N,KD]^T.
// 128x128 tile, BK=32, 4 waves (2x2, wave=64x64), 256 thr, LDS 32KB dbuf
// -> 3 blocks/CU (96KB LDS, V capped 170 via __launch_bounds__(256,3)).
// Issue-early: STAGE(t+1) before COMPUTE(t); vmcnt(0)+s_barrier per tile
// (latency hidden by compute + cross-block TLP). Row-XOR swizzle for 64B
// rows: byte ^= (row&6)<<3 (conflict-free b128, 2-way inherent = free).
// T1 bijective XCD swizzle (nwg%8==0 all instantiations).
// EPI: 0 = per-head LN (eps 1e-6) * QSCALE -> bf16 o_bf [M,CC]
//      1 = KV: cols<CC LN (eps 1e-5) -> Kbf[b][h][na][d]; cols>=CC ->
//          Vt[b][h][d][na] (both bf16)
//      2 = bias -> fp32 o_f [M,CC]
// ---------------------------------------------------------------------------
template <int KD, int EPI, int NXT, int MROWS>
__global__ __launch_bounds__(256, 3) void gemm_bf16(
    const u16* __restrict__ A, const u16* __restrict__ W,
    const float* __restrict__ bias, const float* __restrict__ lnw,
    const float* __restrict__ lnb, u16* __restrict__ o_bf,
    u16* __restrict__ o_bf2, float* __restrict__ o_f) {
  __shared__ u16 LDS[2][8192];  // per buf: A 128x32 (8KB) | B 128x32 (8KB)
  constexpr int nt = KD / 32;
  const int tid = threadIdx.x;
  const int l = tid & 63, wid = tid >> 6;
  const int wr = wid >> 1, wc = wid & 1;  // 2x2 waves of 64x64
  const int g = l >> 4, ql = l & 15;

  // T1 bijective XCD swizzle
  const int orig = (int)blockIdx.x + NXT * (int)blockIdx.y;
  const int q8 = (NXT * (int)gridDim.y) >> 3;
  const int nid = (orig & 7) * q8 + (orig >> 3);
  const int row0 = (nid / NXT) * 128, col0 = (nid % NXT) * 128;

  // staging: 256 thr x 16B = 4KB/issue = 64 rows x 64B; 2 issues per matrix
  const int rs = tid >> 2;  // 0..63 row within issue stripe
  const int cs = tid & 3;   // 16B slot in 64B row
  const int soff = ((cs * 16) ^ ((rs & 6) << 3)) >> 1;  // elems, pre-swizzled

  f32x4 acc[4][4];
#pragma unroll
  for (int m = 0; m < 4; ++m)
#pragma unroll
    for (int n = 0; n < 4; ++n) acc[m][n] = (f32x4){0.f, 0.f, 0.f, 0.f};

  auto STAGE = [&](int buf, int t) {
    const int k0 = t * 32;
    char* lA = (char*)&LDS[buf][0] + tid * 16;
    char* lB = (char*)&LDS[buf][4096] + tid * 16;
#pragma unroll
    for (int j = 0; j < 2; ++j) {
      int r = row0 + j * 64 + rs;
      r = min(r, MROWS - 1);  // M-tail clamp (row&6 swizzle preserved)
      gl2lds16(A + (size_t)r * KD + k0 + soff, lA + j * 4096);
    }
#pragma unroll
    for (int j = 0; j < 2; ++j)
      gl2lds16(W + (size_t)(col0 + j * 64 + rs) * KD + k0 + soff,
               lB + j * 4096);
  };

  auto COMPUTE = [&](int buf) {
    const char* As = (const char*)&LDS[buf][0];
    const char* Bs = (const char*)&LDS[buf][4096];
    bf16x8 af[4], bfv[4];
#pragma unroll
    for (int m = 0; m < 4; ++m) {
      int ra = wr * 64 + m * 16 + ql;
      af[m] = *(const bf16x8*)(As + ra * 64 + ((g * 16) ^ ((ra & 6) << 3)));
    }
#pragma unroll
    for (int n = 0; n < 4; ++n) {
      int rb = wc * 64 + n * 16 + ql;
      bfv[n] = *(const bf16x8*)(Bs + rb * 64 + ((g * 16) ^ ((rb & 6) << 3)));
    }
    __builtin_amdgcn_s_setprio(1);
#pragma unroll
    for (int m = 0; m < 4; ++m)
#pragma unroll
      for (int n = 0; n < 4; ++n)
        acc[m][n] = mfma16(af[m], bfv[n], acc[m][n]);
    __builtin_amdgcn_s_setprio(0);
  };

  STAGE(0, 0);
  asm volatile("s_waitcnt vmcnt(0)" ::: "memory");
  __builtin_amdgcn_s_barrier();
  for (int t = 0; t < nt; t += 2) {
    STAGE(1, t + 1);          // t+1 < nt always (nt even)
    COMPUTE(0);
    asm volatile("s_waitcnt vmcnt(0)" ::: "memory");
    __builtin_amdgcn_s_barrier();
    if (t + 2 < nt) STAGE(0, t + 2);
    COMPUTE(1);
    asm volatile("s_waitcnt vmcnt(0)" ::: "memory");
    __builtin_amdgcn_s_barrier();
  }

  // ---------------- epilogue ----------------
  const int colw = col0 + wc * 64;  // 64-aligned => exactly one head
  float bv[4];
#pragma unroll
  for (int n = 0; n < 4; ++n) bv[n] = bias[colw + n * 16 + ql];

  if constexpr (EPI == 2) {
#pragma unroll
    for (int m = 0; m < 4; ++m)
#pragma unroll
      for (int reg = 0; reg < 4; ++reg) {
        int grow = row0 + wr * 64 + m * 16 + g * 4 + reg;
        if (grow < MROWS) {
#pragma unroll
          for (int n = 0; n < 4; ++n)
            o_f[(size_t)grow * CC + colw + n * 16 + ql] =
                acc[m][n][reg] + bv[n];
        }
      }
    return;
  }

  if constexpr (EPI == 0) {
    float lwv[4], lbv[4];
#pragma unroll
    for (int n = 0; n < 4; ++n) {
      lwv[n] = lnw[n * 16 + ql] * QSCALE;
      lbv[n] = lnb[n * 16 + ql] * QSCALE;
    }
    const int head = colw >> 6;
#pragma unroll
    for (int m = 0; m < 4; ++m)
#pragma unroll
      for (int reg = 0; reg < 4; ++reg) {
        int grow = row0 + wr * 64 + m * 16 + g * 4 + reg;
        if (grow < MROWS) {
          float tv[4], s = 0.f, ss = 0.f;
#pragma unroll
          for (int n = 0; n < 4; ++n) {
            tv[n] = acc[m][n][reg] + bv[n];
            s += tv[n]; ss += tv[n] * tv[n];
          }
#pragma unroll
          for (int off = 1; off < 16; off <<= 1) {
            s  += __shfl_xor(s, off, 16);
            ss += __shfl_xor(ss, off, 16);
          }
          float mean = s * (1.f / 64.f);
          float var  = ss * (1.f / 64.f) - mean * mean;
          float rs_  = rsqrtf(var + 1e-6f);
          u16* dst = o_bf + (size_t)grow * CC + head * 64;
#pragma unroll
          for (int n = 0; n < 4; ++n)
            dst[n * 16 + ql] = f2bf((tv[n] - mean) * rs_ * lwv[n] + lbv[n]);
        }
      }
    return;
  }

  if constexpr (EPI == 1) {
    const bool isK = (colw < CC);
    const int head = (isK ? colw : (colw - CC)) >> 6;
    if (isK) {
      float lwv[4], lbv[4];
#pragma unroll
      for (int n = 0; n < 4; ++n) {
        lwv[n] = lnw[n * 16 + ql];
        lbv[n] = lnb[n * 16 + ql];
      }
#pragma unroll
      for (int m = 0; m < 4; ++m)
#pragma unroll
        for (int reg = 0; reg < 4; ++reg) {
          float tv[4], s = 0.f, ss = 0.f;
#pragma unroll
          for (int n = 0; n < 4; ++n) {
            tv[n] = acc[m][n][reg] + bv[n];
            s += tv[n]; ss += tv[n] * tv[n];
          }
#pragma unroll
          for (int off = 1; off < 16; off <<= 1) {
            s  += __shfl_xor(s, off, 16);
            ss += __shfl_xor(ss, off, 16);
          }
          float mean = s * (1.f / 64.f);
          float var  = ss * (1.f / 64.f) - mean * mean;
          float rs_  = rsqrtf(var + 1e-5f);
          int grow = row0 + wr * 64 + m * 16 + g * 4 + reg;
          int bb = grow >> 8, na = grow & 255;
          u16* dst = o_bf + (size_t)((bb * HH + head) * NAk + na) * DD;
#pragma unroll
          for (int n = 0; n < 4; ++n)
            dst[n * 16 + ql] = f2bf((tv[n] - mean) * rs_ * lwv[n] + lbv[n]);
        }
    } else {
#pragma unroll
      for (int m = 0; m < 4; ++m)
#pragma unroll
        for (int reg = 0; reg < 4; ++reg) {
          int grow = row0 + wr * 64 + m * 16 + g * 4 + reg;
          int bb = grow >> 8, na = grow & 255;
          u16* dst = o_bf2 + (size_t)(bb * HH + head) * DD * NAk + na;
#pragma unroll
          for (int n = 0; n < 4; ++n) {
            int d = n * 16 + ql;
            dst[(size_t)d * NAk] = f2bf(acc[m][n][reg] + bv[n]);
          }
        }
    }
    return;
  }
}

// ---------------------------------------------------------------------------
// MFMA attention (unchanged): PERSISTENT per-(b,h) block. grid=(HH,BB),
// 768 threads = 12 waves. K + Vt staged once into swizzled LDS, waves sweep
// 32-row q-tiles; swapped QK^T, NO-MAX softmax, cvt_pk P pack, deferred 1/l.
// ---------------------------------------------------------------------------
__global__ __launch_bounds__(768) void attn_mfma(
    const u16* __restrict__ Qbf, const u16* __restrict__ Kbf,
    const u16* __restrict__ Vtbf, u16* __restrict__ Obf) {
  __shared__ u16 Ks[256 * 64];    // 32KB [key][d], row-XOR swizzled
  __shared__ u16 Vts[64 * 256];   // 32KB [d][key], row-XOR swizzled
  __shared__ u16 P[12][32][64];   // 48KB per-wave [32 q][64 keys]
  const int tid = threadIdx.x, l = tid & 63, wid = tid >> 6;
  const int g = l >> 4, ql = l & 15;
  const int h = blockIdx.x, b = blockIdx.y;
  const size_t kvbase = (size_t)(b * HH + h) * (NAk * DD);
  const u16* Kp = Kbf + kvbase;
  const u16* Vp = Vtbf + kvbase;
  char* Pw = (char*)&P[wid][0][0];
  const int swz = (ql & 7) << 4;

  for (int idx = tid; idx < 4096; idx += 768) {
    if (idx < 2048) {
      int kr = idx >> 3, kc = idx & 7;
      gl2lds16(Kp + kr * 64 + (((kc * 16) ^ ((kr & 7) << 4)) >> 1),
               (char*)Ks + idx * 16);
    } else {
      int j = idx - 2048;
      int vr = j >> 5, vc = j & 31;
      gl2lds16(Vp + vr * 256 + (((vc * 16) ^ ((vr & 7) << 4)) >> 1),
               (char*)Vts + j * 16);
    }
  }
  __syncthreads();

  const u16* Qb0 = Qbf + (size_t)b * NQb * CC + h * DD;
  u16* Ob0 = Obf + (size_t)b * NQb * CC + h * DD;

  for (int t = wid; t < NTIL; t += 12) {
    const int qr0 = t * 32;
    bf16x8 qf[2][2];
#pragma unroll
    for (int m = 0; m < 2; ++m) {
      int qrow = min(qr0 + m * 16 + ql, NQb - 1);
      const u16* p = Qb0 + (size_t)qrow * CC + g * 8;
      qf[m][0] = *(const bf16x8*)(p);
      qf[m][1] = *(const bf16x8*)(p + 32);
    }

    f32x4 oacc[2][4];
#pragma unroll
    for (int m = 0; m < 2; ++m)
#pragma unroll
      for (int n = 0; n < 4; ++n) oacc[m][n] = (f32x4){0.f, 0.f, 0.f, 0.f};
    float lsum[2] = {0.f, 0.f};

#pragma unroll
    for (int c = 0; c < 4; ++c) {
      f32x4 sf[2][4];
#pragma unroll
      for (int m = 0; m < 2; ++m)
#pragma unroll
        for (int n = 0; n < 4; ++n) sf[m][n] = (f32x4){0.f, 0.f, 0.f, 0.f};
      __builtin_amdgcn_s_setprio(1);
#pragma unroll
      for (int n = 0; n < 4; ++n) {
        const char* kbase = (const char*)Ks + (c * 64 + n * 16 + ql) * 128;
        bf16x8 ka0 = *(const bf16x8*)(kbase + ((g * 16) ^ swz));
        bf16x8 ka1 = *(const bf16x8*)(kbase + ((g * 16 + 64) ^ swz));
        sf[0][n] = mfma16(ka0, qf[0][0], sf[0][n]);
        sf[0][n] = mfma16(ka1, qf[0][1], sf[0][n]);
        sf[1][n] = mfma16(ka0, qf[1][0], sf[1][n]);
        sf[1][n] = mfma16(ka1, qf[1][1], sf[1][n]);
      }
      __builtin_amdgcn_s_setprio(0);

#pragma unroll
      for (int m = 0; m < 2; ++m) {
        float cs = 0.f;
#pragma unroll
        for (int n = 0; n < 4; ++n)
#pragma unroll
          for (int reg = 0; reg < 4; ++reg) {
            float e = exp2f(sf[m][n][reg]);
            sf[m][n][reg] = e;
            cs += e;
          }
        lsum[m] += cs;
        char* rowp = Pw + (m * 16 + ql) * 128;
#pragma unroll
        for (int n = 0; n < 4; ++n) {
          u32 w0 = cvtpk(sf[m][n][0], sf[m][n][1]);
          u32 w1 = cvtpk(sf[m][n][2], sf[m][n][3]);
          *(uint2*)(rowp + ((n * 32 + g * 8) ^ swz)) = make_uint2(w0, w1);
        }
      }

      __builtin_amdgcn_s_setprio(1);
#pragma unroll
      for (int ks = 0; ks < 2; ++ks) {
        bf16x8 pa[2], vb[4];
#pragma unroll
        for (int m = 0; m < 2; ++m)
          pa[m] = *(const bf16x8*)(Pw + (m * 16 + ql) * 128 +
                                   ((ks * 64 + g * 16) ^ swz));
#pragma unroll
        for (int n = 0; n < 4; ++n)
          vb[n] = *(const bf16x8*)((const char*)Vts + (n * 16 + ql) * 512 +
                                   ((c * 128 + ks * 64 + g * 16) ^ swz));
#pragma unroll
        for (int m = 0; m < 2; ++m)
#pragma unroll
          for (int n = 0; n < 4; ++n)
            oacc[m][n] = mfma16(pa[m], vb[n], oacc[m][n]);
      }
      __builtin_amdgcn_s_setprio(0);
    }

#pragma unroll
    for (int m = 0; m < 2; ++m) {
      lsum[m] += __shfl_xor(lsum[m], 16);
      lsum[m] += __shfl_xor(lsum[m], 32);
      float inv[4];
#pragma unroll
      for (int reg = 0; reg < 4; ++reg)
        inv[reg] = 1.f / __shfl(lsum[m], g * 4 + reg);
#pragma unroll
      for (int reg = 0; reg < 4; ++reg) {
        int qrow = qr0 + m * 16 + g * 4 + reg;
        if (qrow < NQb) {
          u16* dst = Ob0 + (size_t)qrow * CC;
#pragma unroll
          for (int n = 0; n < 4; ++n)
            dst[n * 16 + ql] = f2bf(oacc[m][n][reg] * inv[reg]);
        }
      }
    }
  }
}

// ---------------------------------------------------------------------------
extern "C" void kernel_launch(void* const* d_in, const int* in_sizes, int n_in,
                              void* d_out, int out_size, void* d_ws,
                              size_t ws_size, hipStream_t stream) {
  const float* x      = (const float*)d_in[0];
  const float* enc    = (const float*)d_in[1];
  const float* q_w    = (const float*)d_in[2];
  const float* q_b    = (const float*)d_in[3];
  const float* kv_w   = (const float*)d_in[4];
  const float* kv_b   = (const float*)d_in[5];
  const float* proj_w = (const float*)d_in[6];
  const float* proj_b = (const float*)d_in[7];
  const float* qn_w   = (const float*)d_in[8];
  const float* qn_b   = (const float*)d_in[9];
  const float* kn_w   = (const float*)d_in[10];
  const float* kn_b   = (const float*)d_in[11];
  float* out = (float*)d_out;

  u16* ws = (u16*)d_ws;
  size_t off = 0;
  u16* Xbf  = ws + off; off += (size_t)MTOT * CC;   // also reused as O
  u16* Qbf  = ws + off; off += (size_t)MTOT * CC;
  u16* Ebf  = ws + off; off += (size_t)BB * NAk * CE;
  u16* QWb  = ws + off; off += (size_t)CC * CC;
  u16* KVWb = ws + off; off += (size_t)2 * CC * CE;
  u16* PWb  = ws + off; off += (size_t)CC * CC;
  u16* Kbf  = ws + off; off += (size_t)BB * HH * NAk * DD;
  u16* Vtbf = ws + off; off += (size_t)BB * HH * NAk * DD;

  // single fused conversion launch (segments in float4 units)
  const int nx  = (MTOT * CC) / 4;          // 6389760
  const int ne  = (BB * NAk * CE) / 4;      // 786432
  const int nqw = (CC * CC) / 4;            // 262144
  const int nkv = (2 * CC * CE) / 4;        // 393216
  const int npw = (CC * CC) / 4;            // 262144
  conv_all<<<2048, 256, 0, stream>>>(
      x, enc, q_w, kv_w, proj_w, Xbf, Ebf, QWb, KVWb, PWb, nx, nx + ne,
      nx + ne + nqw, nx + ne + nqw + nkv, nx + ne + nqw + nkv + npw);

  // 128x128 tiles; grid.x = col tiles, grid.y = row tiles
  gemm_bf16<CC, 0, 8, MTOT><<<dim3(8, 195), 256, 0, stream>>>(
      Xbf, QWb, q_b, qn_w, qn_b, Qbf, nullptr, nullptr);
  gemm_bf16<CE, 1, 16, BB * NAk><<<dim3(16, 32), 256, 0, stream>>>(
      Ebf, KVWb, kv_b, kn_w, kn_b, Kbf, Vtbf, nullptr);
  attn_mfma<<<dim3(HH, BB), 768, 0, stream>>>(Qbf, Kbf, Vtbf, Xbf);
  gemm_bf16<CC, 2, 8, MTOT><<<dim3(8, 195), 256, 0, stream>>>(
      Xbf, PWb, proj_b, nullptr, nullptr, nullptr, nullptr, out);
}